// Round 1
// baseline (33271.588 us; speedup 1.0000x reference)
//
#include <hip/hip_runtime.h>

#define SEQ   512
#define BATCH 32
#define EMBD  256
#define UNITS 512
#define G4    2048   // 4*UNITS
#define NWGD  128    // K2 workgroups per direction
#define NCOL  16     // 4 gates * 4 units per WG

static constexpr unsigned long long ZX2_OFF   = 0ull;
static constexpr unsigned long long ZX2_BYTES = 2ull * SEQ * NWGD * BATCH * NCOL * 2; // 128 MiB
static constexpr unsigned long long HBUF_OFF  = ZX2_OFF + ZX2_BYTES;
static constexpr unsigned long long HBUF_BYTES= 2ull * SEQ * UNITS * BATCH * 4;       // 64 MiB
static constexpr unsigned long long FLG_OFF   = HBUF_OFF + HBUF_BYTES;
static constexpr unsigned long long FLG_BYTES = 2ull * SEQ * 4;

__device__ __forceinline__ unsigned short f2bf(float f) {
  unsigned int u = __float_as_uint(f);
  u = (u + 0x7FFFu + ((u >> 16) & 1u)) >> 16;
  return (unsigned short)u;
}
__device__ __forceinline__ float bf2f(unsigned short s) {
  return __uint_as_float(((unsigned int)s) << 16);
}

// -------------------- K1: zx = gather(emb,x) @ W + b  (fp32, bf16 out) -----
__global__ __launch_bounds__(256)
void k_zx(const int* __restrict__ x, const float* __restrict__ emb,
          const float* __restrict__ Wf, const float* __restrict__ bf,
          const float* __restrict__ Wb, const float* __restrict__ bb,
          unsigned short* __restrict__ zx2)
{
  const int nb  = blockIdx.x;   // 0..31   64-col block (N)
  const int mb  = blockIdx.y;   // 0..255  64-row block (M = t*32+b)
  const int dir = blockIdx.z;   // 0..1
  const float* __restrict__ W    = dir ? Wb : Wf;
  const float* __restrict__ bias = dir ? bb : bf;
  const int tid = threadIdx.x;
  const int M0 = mb * 64, N0 = nb * 64;

  __shared__ __align__(16) float Ast[32][68]; // A transposed: [k][m]
  __shared__ __align__(16) float Bs [32][68]; // [k][n]
  __shared__ int tok[64];

  if (tid < 64) {
    int m = M0 + tid;
    int t = m >> 5, b = m & 31;
    int s = dir ? (SEQ - 1 - t) : t;
    tok[tid] = x[b * SEQ + s];
  }

  float acc[4][4];
  #pragma unroll
  for (int r = 0; r < 4; ++r)
    #pragma unroll
    for (int c = 0; c < 4; ++c) acc[r][c] = 0.f;

  const int mq = tid >> 4, nq = tid & 15;

  for (int kb = 0; kb < 8; ++kb) {
    __syncthreads();
    { // stage A (gathered, transposed into LDS)
      int m = tid >> 2, q = tid & 3;
      const float* src = emb + (size_t)tok[m] * EMBD + kb * 32 + q * 8;
      float4 v0 = *(const float4*)src;
      float4 v1 = *(const float4*)(src + 4);
      int k0 = q * 8;
      Ast[k0+0][m] = v0.x; Ast[k0+1][m] = v0.y; Ast[k0+2][m] = v0.z; Ast[k0+3][m] = v0.w;
      Ast[k0+4][m] = v1.x; Ast[k0+5][m] = v1.y; Ast[k0+6][m] = v1.z; Ast[k0+7][m] = v1.w;
    }
    { // stage B
      int k = tid >> 3, q = tid & 7;
      const float* src = W + (size_t)(kb*32 + k) * G4 + N0 + q * 8;
      float4 w0 = *(const float4*)src;
      float4 w1 = *(const float4*)(src + 4);
      *(float4*)&Bs[k][q*8]     = w0;
      *(float4*)&Bs[k][q*8 + 4] = w1;
    }
    __syncthreads();
    #pragma unroll 8
    for (int k = 0; k < 32; ++k) {
      float4 a  = *(const float4*)&Ast[k][mq*4];
      float4 bv = *(const float4*)&Bs[k][nq*4];
      acc[0][0] += a.x*bv.x; acc[0][1] += a.x*bv.y; acc[0][2] += a.x*bv.z; acc[0][3] += a.x*bv.w;
      acc[1][0] += a.y*bv.x; acc[1][1] += a.y*bv.y; acc[1][2] += a.y*bv.z; acc[1][3] += a.y*bv.w;
      acc[2][0] += a.z*bv.x; acc[2][1] += a.z*bv.y; acc[2][2] += a.z*bv.z; acc[2][3] += a.z*bv.w;
      acc[3][0] += a.w*bv.x; acc[3][1] += a.w*bv.y; acc[3][2] += a.w*bv.z; acc[3][3] += a.w*bv.w;
    }
  }

  float4 bs4 = *(const float4*)(bias + N0 + nq*4);
  const int g = N0 >> 9;              // whole 64-col block lies in one gate
  const int u = (N0 & 511) + nq * 4;  // unit index (multiple of 4)
  const int w = u >> 2;               // owning K2 workgroup
  #pragma unroll
  for (int r = 0; r < 4; ++r) {
    int m = M0 + mq*4 + r;
    int t = m >> 5, b = m & 31;
    unsigned short p0 = f2bf(acc[r][0] + bs4.x);
    unsigned short p1 = f2bf(acc[r][1] + bs4.y);
    unsigned short p2 = f2bf(acc[r][2] + bs4.z);
    unsigned short p3 = f2bf(acc[r][3] + bs4.w);
    uint2 pk;
    pk.x = (unsigned)p0 | ((unsigned)p1 << 16);
    pk.y = (unsigned)p2 | ((unsigned)p3 << 16);
    size_t off = ((((size_t)dir*SEQ + t)*NWGD + w)*BATCH + b)*NCOL + g*4;
    *(uint2*)(zx2 + off) = pk;
  }
}

// -------------------- K2: sequential LSTM recurrence (fp32) ----------------
__global__ __launch_bounds__(256)
void k_rec(const float* __restrict__ fh, const float* __restrict__ fc,
           const float* __restrict__ bh, const float* __restrict__ bc,
           const float* __restrict__ Uf, const float* __restrict__ Ub,
           const unsigned short* __restrict__ zx2,
           float* __restrict__ hbuf, int* __restrict__ flags,
           float* __restrict__ out)
{
  const int bid = blockIdx.x;
  const int dir = bid >> 7;
  const int w   = bid & 127;
  const int u0  = w * 4;
  const float* __restrict__ U  = dir ? Ub : Uf;
  const float* __restrict__ h0 = dir ? bh : fh;
  const float* __restrict__ c0 = dir ? bc : fc;
  const int tid = threadIdx.x;

  __shared__ __align__(16) float hs[UNITS][BATCH];   // h_{t-1}, [k][b]
  __shared__ __align__(16) float zred[4][BATCH][20]; // per-wave partials (padded)
  __shared__ float cst[BATCH * 4];                   // cell state slice

  float* __restrict__ hring = hbuf + (size_t)dir * SEQ * UNITS * BATCH;
  int*   __restrict__ done  = flags + dir * SEQ;
  const unsigned short* __restrict__ zxw =
      zx2 + (((size_t)dir * SEQ) * NWGD + w) * (BATCH * NCOL);
  const size_t ZXT = (size_t)NWGD * BATCH * NCOL;   // per-step zx stride

  if (tid < 128) {
    int b = tid & 31, uu = tid >> 5;
    cst[b*4 + uu] = c0[b*UNITS + u0 + uu];
  }
  for (int i = tid; i < UNITS*BATCH; i += 256) {  // stage h0 (transposed)
    int uu = i >> 5, b = i & 31;
    hs[uu][b] = h0[b*UNITS + uu];
  }
  __syncthreads();

  const int b  = tid & 31;
  const int kg = tid >> 5;   // k-group 0..7 (64 k each)
  const int wv = tid >> 6;   // wave id
  const float* __restrict__ Ubase = U + (size_t)(kg * 64) * G4 + u0;

  for (int t = 0; t < SEQ; ++t) {
    float acc[16];
    #pragma unroll
    for (int c = 0; c < 16; ++c) acc[c] = 0.f;
    const float* Up = Ubase;
    const float* hp = &hs[kg*64][b];
    #pragma unroll 2
    for (int kk = 0; kk < 64; ++kk) {
      float hv = *hp; hp += BATCH;
      float4 q0 = *(const float4*)(Up);
      float4 q1 = *(const float4*)(Up + 512);
      float4 q2 = *(const float4*)(Up + 1024);
      float4 q3 = *(const float4*)(Up + 1536);
      Up += G4;
      acc[ 0] += hv*q0.x; acc[ 1] += hv*q0.y; acc[ 2] += hv*q0.z; acc[ 3] += hv*q0.w;
      acc[ 4] += hv*q1.x; acc[ 5] += hv*q1.y; acc[ 6] += hv*q1.z; acc[ 7] += hv*q1.w;
      acc[ 8] += hv*q2.x; acc[ 9] += hv*q2.y; acc[10] += hv*q2.z; acc[11] += hv*q2.w;
      acc[12] += hv*q3.x; acc[13] += hv*q3.y; acc[14] += hv*q3.z; acc[15] += hv*q3.w;
    }
    #pragma unroll
    for (int c = 0; c < 16; ++c) acc[c] += __shfl_xor(acc[c], 32);
    if ((tid & 63) < 32) {
      *(float4*)&zred[wv][b][ 0] = make_float4(acc[ 0], acc[ 1], acc[ 2], acc[ 3]);
      *(float4*)&zred[wv][b][ 4] = make_float4(acc[ 4], acc[ 5], acc[ 6], acc[ 7]);
      *(float4*)&zred[wv][b][ 8] = make_float4(acc[ 8], acc[ 9], acc[10], acc[11]);
      *(float4*)&zred[wv][b][12] = make_float4(acc[12], acc[13], acc[14], acc[15]);
    }
    __syncthreads();

    if (tid < 128) {
      int b2 = tid & 31, uu = tid >> 5;
      float z[4];
      #pragma unroll
      for (int g = 0; g < 4; ++g) {
        float s = zred[0][b2][g*4+uu] + zred[1][b2][g*4+uu]
                + zred[2][b2][g*4+uu] + zred[3][b2][g*4+uu];
        s += bf2f(zxw[(size_t)t*ZXT + (size_t)b2*NCOL + g*4 + uu]);
        z[g] = s;
      }
      float ig = 1.f / (1.f + __expf(-z[0]));
      float fg = 1.f / (1.f + __expf(-z[1]));
      float gg = tanhf(z[2]);
      float og = 1.f / (1.f + __expf(-z[3]));
      float cn = fg * cst[b2*4+uu] + ig * gg;
      cst[b2*4+uu] = cn;
      float hn = og * tanhf(cn);
      hring[(size_t)t*(UNITS*BATCH) + (size_t)(u0+uu)*BATCH + b2] = hn;
      int sidx = dir ? (SEQ-1 - t) : t;
      out[((size_t)b2*SEQ + sidx)*1024 + dir*512 + u0 + uu] = hn;
      if (t == SEQ-1) {
        size_t base = (size_t)BATCH*SEQ*1024;
        out[base + (size_t)(2*dir  )*BATCH*UNITS + (size_t)b2*UNITS + u0+uu] = hn;
        out[base + (size_t)(2*dir+1)*BATCH*UNITS + (size_t)b2*UNITS + u0+uu] = cn;
      }
    }
    __threadfence();          // publish h slice (device scope)
    __syncthreads();
    if (tid == 0)
      __hip_atomic_fetch_add(&done[t], 1, __ATOMIC_RELEASE, __HIP_MEMORY_SCOPE_AGENT);

    if (t < SEQ-1) {
      if (tid == 0) {
        int guard = 0;
        while (__hip_atomic_load(&done[t], __ATOMIC_ACQUIRE, __HIP_MEMORY_SCOPE_AGENT) < NWGD
               && ++guard < (1 << 24)) {
          __builtin_amdgcn_s_sleep(2);
        }
      }
      __syncthreads();
      __threadfence();        // acquire-side fence / L1 invalidate
      const float* src = hring + (size_t)t * (UNITS*BATCH);
      for (int i = tid; i < (UNITS*BATCH)/4; i += 256) {
        float4 v = *(const float4*)(src + (size_t)i*4);
        *(float4*)(&hs[0][0] + (size_t)i*4) = v;
      }
      __syncthreads();
    }
  }
}

// -------------------- launch ----------------------------------------------
extern "C" void kernel_launch(void* const* d_in, const int* in_sizes, int n_in,
                              void* d_out, int out_size, void* d_ws, size_t ws_size,
                              hipStream_t stream)
{
  const int*   x   = (const int*)  d_in[0];
  const float* fh  = (const float*)d_in[1];
  const float* fc  = (const float*)d_in[2];
  const float* bh  = (const float*)d_in[3];
  const float* bc  = (const float*)d_in[4];
  const float* emb = (const float*)d_in[5];
  const float* Wf  = (const float*)d_in[6];
  const float* Uf  = (const float*)d_in[7];
  const float* bf  = (const float*)d_in[8];
  const float* Wb  = (const float*)d_in[9];
  const float* Ub  = (const float*)d_in[10];
  const float* bb  = (const float*)d_in[11];
  float* out = (float*)d_out;

  if (ws_size < FLG_OFF + FLG_BYTES) return;  // workspace too small: fail loudly

  unsigned short* zx2   = (unsigned short*)((char*)d_ws + ZX2_OFF);
  float*          hbuf  = (float*)((char*)d_ws + HBUF_OFF);
  int*            flags = (int*)((char*)d_ws + FLG_OFF);

  hipMemsetAsync(flags, 0, FLG_BYTES, stream);
  k_zx <<<dim3(32, 256, 2), 256, 0, stream>>>(x, emb, Wf, bf, Wb, bb, zx2);
  k_rec<<<dim3(256),        256, 0, stream>>>(fh, fc, bh, bc, Uf, Ub, zx2, hbuf, flags, out);
}

// Round 2
// 5456.805 us; speedup vs baseline: 6.0973x; 6.0973x over previous
//
#include <hip/hip_runtime.h>

#define SEQ   512
#define BATCH 32
#define EMBD  256
#define UNITS 512
#define G4    2048   // 4*UNITS
#define NW1   128    // K1 zx slot count (units/4) — round-1 layout kept
#define NW2   64     // K2 workgroups per direction
#define UPW   8      // units per K2 workgroup

typedef short  short8 __attribute__((ext_vector_type(8)));
typedef float  f32x4  __attribute__((ext_vector_type(4)));

static constexpr unsigned long long ZX2_OFF   = 0ull;
static constexpr unsigned long long ZX2_BYTES = 2ull * SEQ * NW1 * BATCH * 16 * 2; // 128 MiB
static constexpr unsigned long long HB_OFF    = ZX2_OFF + ZX2_BYTES;
static constexpr unsigned long long HB_BYTES  = 2ull * SEQ * BATCH * UNITS * 2;    // 32 MiB bf16
static constexpr unsigned long long FLG_OFF   = HB_OFF + HB_BYTES;
static constexpr unsigned long long FLG_BYTES = 2ull * SEQ * 4;

__device__ __forceinline__ unsigned short f2bf(float f) {
  unsigned int u = __float_as_uint(f);
  u = (u + 0x7FFFu + ((u >> 16) & 1u)) >> 16;
  return (unsigned short)u;
}
__device__ __forceinline__ float bf2f(unsigned short s) {
  return __uint_as_float(((unsigned int)s) << 16);
}

// -------------------- K1: zx = gather(emb,x) @ W + b  (fp32, bf16 out) -----
// unchanged from round 1 (verified)
__global__ __launch_bounds__(256)
void k_zx(const int* __restrict__ x, const float* __restrict__ emb,
          const float* __restrict__ Wf, const float* __restrict__ bf,
          const float* __restrict__ Wb, const float* __restrict__ bb,
          unsigned short* __restrict__ zx2)
{
  const int nb  = blockIdx.x;   // 0..31   64-col block (N)
  const int mb  = blockIdx.y;   // 0..255  64-row block (M = t*32+b)
  const int dir = blockIdx.z;   // 0..1
  const float* __restrict__ W    = dir ? Wb : Wf;
  const float* __restrict__ bias = dir ? bb : bf;
  const int tid = threadIdx.x;
  const int M0 = mb * 64, N0 = nb * 64;

  __shared__ __align__(16) float Ast[32][68];
  __shared__ __align__(16) float Bs [32][68];
  __shared__ int tok[64];

  if (tid < 64) {
    int m = M0 + tid;
    int t = m >> 5, b = m & 31;
    int s = dir ? (SEQ - 1 - t) : t;
    tok[tid] = x[b * SEQ + s];
  }

  float acc[4][4];
  #pragma unroll
  for (int r = 0; r < 4; ++r)
    #pragma unroll
    for (int c = 0; c < 4; ++c) acc[r][c] = 0.f;

  const int mq = tid >> 4, nq = tid & 15;

  for (int kb = 0; kb < 8; ++kb) {
    __syncthreads();
    {
      int m = tid >> 2, q = tid & 3;
      const float* src = emb + (size_t)tok[m] * EMBD + kb * 32 + q * 8;
      float4 v0 = *(const float4*)src;
      float4 v1 = *(const float4*)(src + 4);
      int k0 = q * 8;
      Ast[k0+0][m] = v0.x; Ast[k0+1][m] = v0.y; Ast[k0+2][m] = v0.z; Ast[k0+3][m] = v0.w;
      Ast[k0+4][m] = v1.x; Ast[k0+5][m] = v1.y; Ast[k0+6][m] = v1.z; Ast[k0+7][m] = v1.w;
    }
    {
      int k = tid >> 3, q = tid & 7;
      const float* src = W + (size_t)(kb*32 + k) * G4 + N0 + q * 8;
      float4 w0 = *(const float4*)src;
      float4 w1 = *(const float4*)(src + 4);
      *(float4*)&Bs[k][q*8]     = w0;
      *(float4*)&Bs[k][q*8 + 4] = w1;
    }
    __syncthreads();
    #pragma unroll 8
    for (int k = 0; k < 32; ++k) {
      float4 a  = *(const float4*)&Ast[k][mq*4];
      float4 bv = *(const float4*)&Bs[k][nq*4];
      acc[0][0] += a.x*bv.x; acc[0][1] += a.x*bv.y; acc[0][2] += a.x*bv.z; acc[0][3] += a.x*bv.w;
      acc[1][0] += a.y*bv.x; acc[1][1] += a.y*bv.y; acc[1][2] += a.y*bv.z; acc[1][3] += a.y*bv.w;
      acc[2][0] += a.z*bv.x; acc[2][1] += a.z*bv.y; acc[2][2] += a.z*bv.z; acc[2][3] += a.z*bv.w;
      acc[3][0] += a.w*bv.x; acc[3][1] += a.w*bv.y; acc[3][2] += a.w*bv.z; acc[3][3] += a.w*bv.w;
    }
  }

  float4 bs4 = *(const float4*)(bias + N0 + nq*4);
  const int g = N0 >> 9;
  const int u = (N0 & 511) + nq * 4;
  const int w = u >> 2;
  #pragma unroll
  for (int r = 0; r < 4; ++r) {
    int m = M0 + mq*4 + r;
    int t = m >> 5, b = m & 31;
    unsigned short p0 = f2bf(acc[r][0] + bs4.x);
    unsigned short p1 = f2bf(acc[r][1] + bs4.y);
    unsigned short p2 = f2bf(acc[r][2] + bs4.z);
    unsigned short p3 = f2bf(acc[r][3] + bs4.w);
    uint2 pk;
    pk.x = (unsigned)p0 | ((unsigned)p1 << 16);
    pk.y = (unsigned)p2 | ((unsigned)p3 << 16);
    size_t off = ((((size_t)dir*SEQ + t)*NW1 + w)*BATCH + b)*16 + g*4;
    *(uint2*)(zx2 + off) = pk;
  }
}

// -------------------- K2: recurrence, U-in-registers + bf16 MFMA -----------
__global__ __launch_bounds__(256, 1)
void k_rec2(const float* __restrict__ fh, const float* __restrict__ fc,
            const float* __restrict__ bh, const float* __restrict__ bc,
            const float* __restrict__ Uf, const float* __restrict__ Ub,
            const unsigned short* __restrict__ zx2,
            unsigned short* __restrict__ hring_all, int* __restrict__ flags,
            float* __restrict__ out)
{
  const int bid = blockIdx.x;      // 0..127
  const int dir = bid >> 6;
  const int w   = bid & 63;
  const int u0  = w * UPW;
  const int tid = threadIdx.x;
  const int l   = tid & 63;
  const int wid = tid >> 6;
  const int mt  = wid & 1;         // M-tile (b 0..15 / 16..31)
  const int ct  = wid >> 1;        // col-tile (gates i,f / g,o)
  const float* __restrict__ U  = dir ? Ub : Uf;
  const float* __restrict__ h0 = dir ? bh : fh;
  const float* __restrict__ c0 = dir ? bc : fc;

  __shared__ __align__(16) unsigned short hs[BATCH * UNITS]; // swizzled [b][k] bf16
  __shared__ __align__(16) float zbuf[BATCH][36];
  __shared__ float cst[BATCH][UPW];

  unsigned short* __restrict__ hring = hring_all + (size_t)dir * SEQ * BATCH * UNITS;
  int* __restrict__ done = flags + dir * SEQ;
  const unsigned short* __restrict__ zxd =
      zx2 + ((size_t)dir * SEQ) * (NW1 * BATCH * 16);

  // ---- preload U slice as bf16 MFMA B-fragments, hi/lo split --------------
  // B layout (16x16x32): lane l holds col = l&15, k = (l>>4)*8 + j (j=0..7).
  // local col (l&15) -> gate g = ct*2 + ((l&15)>>3), unit uu = l&7.
  const int colg = (l & 15) >> 3;
  const int krow = (l >> 4) * 8;
  const size_t gcol = (size_t)(ct * 2 + colg) * 512 + u0 + (l & 7);
  short8 uhi[16], ulo[16];
  #pragma unroll
  for (int s = 0; s < 16; ++s) {
    const float* up = U + (size_t)(s * 32 + krow) * G4 + gcol;
    short8 hi8, lo8;
    #pragma unroll
    for (int j = 0; j < 8; ++j) {
      float uv = up[(size_t)j * G4];
      unsigned short h16 = f2bf(uv);
      float rem = uv - bf2f(h16);
      hi8[j] = (short)h16;
      lo8[j] = (short)f2bf(rem);
    }
    uhi[s] = hi8; ulo[s] = lo8;
  }

  // ---- init cell state (256 threads == 32b x 8u) ---------------------------
  {
    int b = tid & 31, uu = tid >> 5;
    cst[b][uu] = c0[b * UNITS + u0 + uu];
  }

  // ---- stage h0 (fp32 -> bf16, swizzled 16B groups) ------------------------
  {
    int b = tid >> 3, q = tid & 7, bx = b & 7;
    const float* src = h0 + (size_t)b * UNITS + q * 64;
    #pragma unroll
    for (int i = 0; i < 8; ++i) {
      float4 v0 = *(const float4*)(src + i * 8);
      float4 v1 = *(const float4*)(src + i * 8 + 4);
      short8 pk;
      pk[0]=(short)f2bf(v0.x); pk[1]=(short)f2bf(v0.y);
      pk[2]=(short)f2bf(v0.z); pk[3]=(short)f2bf(v0.w);
      pk[4]=(short)f2bf(v1.x); pk[5]=(short)f2bf(v1.y);
      pk[6]=(short)f2bf(v1.z); pk[7]=(short)f2bf(v1.w);
      int grp = (q * 8 + i) ^ bx;
      *(short8*)(&hs[b * UNITS + grp * 8]) = pk;
    }
  }
  __syncthreads();

  // gate-phase mapping
  const int gb  = tid & 31;
  const int guu = tid >> 5;
  const int slot = 2 * w + (guu >> 2);
  const int zxi0 = (slot * BATCH + gb) * 16 + (guu & 3);
  // A-read per-lane constants
  const int arow  = 16 * mt + (l & 15);
  const int a_bx  = arow & 7;
  const unsigned short* hsrow = hs + arow * UNITS;
  const int agrp0 = l >> 4;

  for (int t = 0; t < SEQ; ++t) {
    // prefetch zx for this step (static data -> safe across inv)
    const unsigned short* zxt = zxd + (size_t)t * (NW1 * BATCH * 16) + zxi0;
    unsigned short zx_i = zxt[0], zx_f = zxt[4], zx_g = zxt[8], zx_o = zxt[12];

    if (t > 0) {
      if (tid == 0) {
        int guard = 0;
        while (__hip_atomic_load(&done[t-1], __ATOMIC_ACQUIRE, __HIP_MEMORY_SCOPE_AGENT) < NW2
               && ++guard < (1 << 24)) {
          __builtin_amdgcn_s_sleep(2);
        }
      }
      __syncthreads();
      // stage h_{t-1} broadcast: 32 KB bf16 -> LDS (swizzled)
      int b = tid >> 3, q = tid & 7, bx = b & 7;
      const unsigned short* src = hring + ((size_t)(t - 1) * BATCH + b) * UNITS + q * 64;
      #pragma unroll
      for (int i = 0; i < 8; ++i) {
        short8 v = *(const short8*)(src + i * 8);
        int grp = (q * 8 + i) ^ bx;
        *(short8*)(&hs[b * UNITS + grp * 8]) = v;
      }
      __syncthreads();
    }

    // ---- z = h · (Uhi + Ulo) via MFMA ----
    f32x4 acc = {0.f, 0.f, 0.f, 0.f};
    #pragma unroll
    for (int s = 0; s < 16; ++s) {
      int grp = (4 * s + agrp0) ^ a_bx;
      short8 a = *(const short8*)(hsrow + grp * 8);
      acc = __builtin_amdgcn_mfma_f32_16x16x32_bf16(a, uhi[s], acc, 0, 0, 0);
      acc = __builtin_amdgcn_mfma_f32_16x16x32_bf16(a, ulo[s], acc, 0, 0, 0);
    }
    // C/D: col = lane&15, row = (lane>>4)*4 + reg  [verified layout]
    #pragma unroll
    for (int r = 0; r < 4; ++r)
      zbuf[16 * mt + (l >> 4) * 4 + r][ct * 16 + (l & 15)] = acc[r];
    __syncthreads();

    // ---- gates: thread = (gb, guu) ----
    float zi = zbuf[gb][     guu] + bf2f(zx_i);
    float zf = zbuf[gb][ 8 + guu] + bf2f(zx_f);
    float zg = zbuf[gb][16 + guu] + bf2f(zx_g);
    float zo = zbuf[gb][24 + guu] + bf2f(zx_o);
    float ig = 1.f / (1.f + __expf(-zi));
    float fg = 1.f / (1.f + __expf(-zf));
    float gg = tanhf(zg);
    float og = 1.f / (1.f + __expf(-zo));
    float cn = fg * cst[gb][guu] + ig * gg;
    cst[gb][guu] = cn;
    float hn = og * tanhf(cn);
    hring[((size_t)t * BATCH + gb) * UNITS + u0 + guu] = f2bf(hn);
    __syncthreads();
    if (tid == 0)
      __hip_atomic_fetch_add(&done[t], 1, __ATOMIC_RELEASE, __HIP_MEMORY_SCOPE_AGENT);

    // out writes off the release critical path
    int sidx = dir ? (SEQ - 1 - t) : t;
    out[((size_t)gb * SEQ + sidx) * 1024 + dir * 512 + u0 + guu] = hn;
    if (t == SEQ - 1) {
      size_t base = (size_t)BATCH * SEQ * 1024;
      out[base + (size_t)(2*dir  ) * BATCH * UNITS + (size_t)gb * UNITS + u0 + guu] = hn;
      out[base + (size_t)(2*dir+1) * BATCH * UNITS + (size_t)gb * UNITS + u0 + guu] = cn;
    }
  }
}

// -------------------- launch ----------------------------------------------
extern "C" void kernel_launch(void* const* d_in, const int* in_sizes, int n_in,
                              void* d_out, int out_size, void* d_ws, size_t ws_size,
                              hipStream_t stream)
{
  const int*   x   = (const int*)  d_in[0];
  const float* fh  = (const float*)d_in[1];
  const float* fc  = (const float*)d_in[2];
  const float* bh  = (const float*)d_in[3];
  const float* bc  = (const float*)d_in[4];
  const float* emb = (const float*)d_in[5];
  const float* Wf  = (const float*)d_in[6];
  const float* Uf  = (const float*)d_in[7];
  const float* bf  = (const float*)d_in[8];
  const float* Wb  = (const float*)d_in[9];
  const float* Ub  = (const float*)d_in[10];
  const float* bb  = (const float*)d_in[11];
  float* out = (float*)d_out;

  if (ws_size < FLG_OFF + FLG_BYTES) return;

  unsigned short* zx2   = (unsigned short*)((char*)d_ws + ZX2_OFF);
  unsigned short* hring = (unsigned short*)((char*)d_ws + HB_OFF);
  int*            flags = (int*)((char*)d_ws + FLG_OFF);

  hipMemsetAsync(flags, 0, FLG_BYTES, stream);
  k_zx  <<<dim3(32, 256, 2), 256, 0, stream>>>(x, emb, Wf, bf, Wb, bb, zx2);
  k_rec2<<<dim3(128),        256, 0, stream>>>(fh, fc, bh, bc, Uf, Ub, zx2, hring, flags, out);
}

// Round 3
// 4710.554 us; speedup vs baseline: 7.0632x; 1.1584x over previous
//
#include <hip/hip_runtime.h>

#define SEQ   512
#define BATCH 32
#define EMBD  256
#define UNITS 512
#define G4    2048   // 4*UNITS
#define NW1   128    // K1 zx slot count (units/4) — round-1 layout kept
#define NW2   64     // K2 workgroups per direction
#define UPW   8      // units per K2 workgroup
#define HSTR  520    // LDS h row stride in shorts (512 + 8 => +1 bank quad)

typedef short  short8 __attribute__((ext_vector_type(8)));
typedef float  f32x4  __attribute__((ext_vector_type(4)));

static constexpr unsigned long long ZX2_OFF   = 0ull;
static constexpr unsigned long long ZX2_BYTES = 2ull * SEQ * NW1 * BATCH * 16 * 2; // 128 MiB
static constexpr unsigned long long HB_OFF    = ZX2_OFF + ZX2_BYTES;
static constexpr unsigned long long HB_BYTES  = 2ull * SEQ * BATCH * UNITS * 2;    // 32 MiB bf16
static constexpr unsigned long long FLG_OFF   = HB_OFF + HB_BYTES;
static constexpr unsigned long long FLG_BYTES = 2ull * SEQ * 4;

__device__ __forceinline__ unsigned short f2bf(float f) {
  unsigned int u = __float_as_uint(f);
  u = (u + 0x7FFFu + ((u >> 16) & 1u)) >> 16;
  return (unsigned short)u;
}
__device__ __forceinline__ float bf2f(unsigned short s) {
  return __uint_as_float(((unsigned int)s) << 16);
}

// -------------------- K1: zx = gather(emb,x) @ W + b  (fp32, bf16 out) -----
// unchanged (verified rounds 1-2)
__global__ __launch_bounds__(256)
void k_zx(const int* __restrict__ x, const float* __restrict__ emb,
          const float* __restrict__ Wf, const float* __restrict__ bf,
          const float* __restrict__ Wb, const float* __restrict__ bb,
          unsigned short* __restrict__ zx2)
{
  const int nb  = blockIdx.x;
  const int mb  = blockIdx.y;
  const int dir = blockIdx.z;
  const float* __restrict__ W    = dir ? Wb : Wf;
  const float* __restrict__ bias = dir ? bb : bf;
  const int tid = threadIdx.x;
  const int M0 = mb * 64, N0 = nb * 64;

  __shared__ __align__(16) float Ast[32][68];
  __shared__ __align__(16) float Bs [32][68];
  __shared__ int tok[64];

  if (tid < 64) {
    int m = M0 + tid;
    int t = m >> 5, b = m & 31;
    int s = dir ? (SEQ - 1 - t) : t;
    tok[tid] = x[b * SEQ + s];
  }

  float acc[4][4];
  #pragma unroll
  for (int r = 0; r < 4; ++r)
    #pragma unroll
    for (int c = 0; c < 4; ++c) acc[r][c] = 0.f;

  const int mq = tid >> 4, nq = tid & 15;

  for (int kb = 0; kb < 8; ++kb) {
    __syncthreads();
    {
      int m = tid >> 2, q = tid & 3;
      const float* src = emb + (size_t)tok[m] * EMBD + kb * 32 + q * 8;
      float4 v0 = *(const float4*)src;
      float4 v1 = *(const float4*)(src + 4);
      int k0 = q * 8;
      Ast[k0+0][m] = v0.x; Ast[k0+1][m] = v0.y; Ast[k0+2][m] = v0.z; Ast[k0+3][m] = v0.w;
      Ast[k0+4][m] = v1.x; Ast[k0+5][m] = v1.y; Ast[k0+6][m] = v1.z; Ast[k0+7][m] = v1.w;
    }
    {
      int k = tid >> 3, q = tid & 7;
      const float* src = W + (size_t)(kb*32 + k) * G4 + N0 + q * 8;
      float4 w0 = *(const float4*)src;
      float4 w1 = *(const float4*)(src + 4);
      *(float4*)&Bs[k][q*8]     = w0;
      *(float4*)&Bs[k][q*8 + 4] = w1;
    }
    __syncthreads();
    #pragma unroll 8
    for (int k = 0; k < 32; ++k) {
      float4 a  = *(const float4*)&Ast[k][mq*4];
      float4 bv = *(const float4*)&Bs[k][nq*4];
      acc[0][0] += a.x*bv.x; acc[0][1] += a.x*bv.y; acc[0][2] += a.x*bv.z; acc[0][3] += a.x*bv.w;
      acc[1][0] += a.y*bv.x; acc[1][1] += a.y*bv.y; acc[1][2] += a.y*bv.z; acc[1][3] += a.y*bv.w;
      acc[2][0] += a.z*bv.x; acc[2][1] += a.z*bv.y; acc[2][2] += a.z*bv.z; acc[2][3] += a.z*bv.w;
      acc[3][0] += a.w*bv.x; acc[3][1] += a.w*bv.y; acc[3][2] += a.w*bv.z; acc[3][3] += a.w*bv.w;
    }
  }

  float4 bs4 = *(const float4*)(bias + N0 + nq*4);
  const int g = N0 >> 9;
  const int u = (N0 & 511) + nq * 4;
  const int w = u >> 2;
  #pragma unroll
  for (int r = 0; r < 4; ++r) {
    int m = M0 + mq*4 + r;
    int t = m >> 5, b = m & 31;
    unsigned short p0 = f2bf(acc[r][0] + bs4.x);
    unsigned short p1 = f2bf(acc[r][1] + bs4.y);
    unsigned short p2 = f2bf(acc[r][2] + bs4.z);
    unsigned short p3 = f2bf(acc[r][3] + bs4.w);
    uint2 pk;
    pk.x = (unsigned)p0 | ((unsigned)p1 << 16);
    pk.y = (unsigned)p2 | ((unsigned)p3 << 16);
    size_t off = ((((size_t)dir*SEQ + t)*NW1 + w)*BATCH + b)*16 + g*4;
    *(uint2*)(zx2 + off) = pk;
  }
}

// -------------------- K2: recurrence, U-in-registers + bf16 MFMA -----------
__global__ __launch_bounds__(256, 1)
void k_rec2(const float* __restrict__ fh, const float* __restrict__ fc,
            const float* __restrict__ bh, const float* __restrict__ bc,
            const float* __restrict__ Uf, const float* __restrict__ Ub,
            const unsigned short* __restrict__ zx2,
            unsigned short* __restrict__ hring_all, int* __restrict__ flags,
            float* __restrict__ out)
{
  const int bid = blockIdx.x;      // 0..127
  const int dir = bid >> 6;
  const int w   = bid & 63;
  const int u0  = w * UPW;
  const int tid = threadIdx.x;
  const int l   = tid & 63;
  const int wid = tid >> 6;
  const int mt  = wid & 1;         // M-tile (b 0..15 / 16..31)
  const int ct  = wid >> 1;        // col-tile (gates i,f / g,o)
  const float* __restrict__ U  = dir ? Ub : Uf;
  const float* __restrict__ h0 = dir ? bh : fh;
  const float* __restrict__ c0 = dir ? bc : fc;

  __shared__ __align__(16) unsigned short hs[BATCH * HSTR]; // [b][k] bf16, +16B row pad
  __shared__ __align__(16) float zbuf[BATCH][33];
  __shared__ float cst[BATCH][9];

  unsigned short* __restrict__ hring = hring_all + (size_t)dir * SEQ * BATCH * UNITS;
  int* __restrict__ done = flags + dir * SEQ;
  const unsigned short* __restrict__ zxd =
      zx2 + ((size_t)dir * SEQ) * (NW1 * BATCH * 16);

  // ---- preload U slice as bf16 MFMA B-fragments, hi/lo split --------------
  // B layout (16x16x32): lane l holds col = l&15, k = (l>>4)*8 + j (j=0..7).
  const int colg = (l & 15) >> 3;
  const int krow = (l >> 4) * 8;
  const size_t gcol = (size_t)(ct * 2 + colg) * 512 + u0 + (l & 7);
  short8 uhi[16], ulo[16];
  #pragma unroll
  for (int s = 0; s < 16; ++s) {
    const float* up = U + (size_t)(s * 32 + krow) * G4 + gcol;
    short8 hi8, lo8;
    #pragma unroll
    for (int j = 0; j < 8; ++j) {
      float uv = up[(size_t)j * G4];
      unsigned short h16 = f2bf(uv);
      float rem = uv - bf2f(h16);
      hi8[j] = (short)h16;
      lo8[j] = (short)f2bf(rem);
    }
    uhi[s] = hi8; ulo[s] = lo8;
  }

  // ---- init cell state ------------------------------------------------------
  {
    int b = tid & 31, uu = tid >> 5;
    cst[b][uu] = c0[b * UNITS + u0 + uu];
  }

  // ---- stage h0 (fp32 -> bf16), padded rows, no XOR -------------------------
  // thread: row r = tid>>3 (0..31), col base c0q = tid&7; 8 iterations cover 64 groups
  {
    int r = tid >> 3, c0q = tid & 7;
    const float* src = h0 + (size_t)r * UNITS;
    #pragma unroll
    for (int i = 0; i < 8; ++i) {
      int c = i * 8 + c0q;           // 16B group index 0..63
      float4 v0 = *(const float4*)(src + c * 8);
      float4 v1 = *(const float4*)(src + c * 8 + 4);
      short8 pk;
      pk[0]=(short)f2bf(v0.x); pk[1]=(short)f2bf(v0.y);
      pk[2]=(short)f2bf(v0.z); pk[3]=(short)f2bf(v0.w);
      pk[4]=(short)f2bf(v1.x); pk[5]=(short)f2bf(v1.y);
      pk[6]=(short)f2bf(v1.z); pk[7]=(short)f2bf(v1.w);
      *(short8*)(&hs[r * HSTR + c * 8]) = pk;
    }
  }
  __syncthreads();

  // gate-phase mapping
  const int gb  = tid & 31;
  const int guu = tid >> 5;
  const int slot = 2 * w + (guu >> 2);
  const int zxi0 = (slot * BATCH + gb) * 16 + (guu & 3);
  // A-read per-lane constants
  const int arow  = 16 * mt + (l & 15);
  const unsigned short* hsrow = hs + arow * HSTR;
  const int agrp0 = l >> 4;
  // staging constants
  const int sr = tid >> 3, sc0 = tid & 7;

  for (int t = 0; t < SEQ; ++t) {
    // prefetch zx for this step into registers (static data)
    const unsigned short* zxt = zxd + (size_t)t * (NW1 * BATCH * 16) + zxi0;
    unsigned short zx_i = zxt[0], zx_f = zxt[4], zx_g = zxt[8], zx_o = zxt[12];

    if (t > 0) {
      if (tid == 0) {
        // relaxed RMW poll: resolves at coherence point, no per-poll L2 inv
        int guard = 0;
        while (__hip_atomic_fetch_add(&done[t-1], 0, __ATOMIC_RELAXED,
                                      __HIP_MEMORY_SCOPE_AGENT) < NW2
               && ++guard < (1 << 22)) {
          __builtin_amdgcn_s_sleep(4);
        }
        __builtin_amdgcn_fence(__ATOMIC_ACQUIRE, "agent");  // one L2 inv per step
      }
      __syncthreads();
      // stage h_{t-1} broadcast: 32 KB bf16 -> LDS (padded rows)
      const unsigned short* src = hring + ((size_t)(t - 1) * BATCH + sr) * UNITS;
      #pragma unroll
      for (int i = 0; i < 8; ++i) {
        int c = i * 8 + sc0;
        short8 v = *(const short8*)(src + c * 8);
        *(short8*)(&hs[sr * HSTR + c * 8]) = v;
      }
      __syncthreads();
    }

    // ---- z = h · (Uhi + Ulo) via MFMA ----
    f32x4 acc = {0.f, 0.f, 0.f, 0.f};
    #pragma unroll
    for (int s = 0; s < 16; ++s) {
      short8 a = *(const short8*)(hsrow + (4 * s + agrp0) * 8);
      acc = __builtin_amdgcn_mfma_f32_16x16x32_bf16(a, uhi[s], acc, 0, 0, 0);
      acc = __builtin_amdgcn_mfma_f32_16x16x32_bf16(a, ulo[s], acc, 0, 0, 0);
    }
    // C/D: col = lane&15, row = (lane>>4)*4 + reg  [verified layout]
    #pragma unroll
    for (int r = 0; r < 4; ++r)
      zbuf[16 * mt + (l >> 4) * 4 + r][ct * 16 + (l & 15)] = acc[r];
    __syncthreads();

    // ---- gates: thread = (gb, guu) ----
    float zi = zbuf[gb][     guu] + bf2f(zx_i);
    float zf = zbuf[gb][ 8 + guu] + bf2f(zx_f);
    float zg = zbuf[gb][16 + guu] + bf2f(zx_g);
    float zo = zbuf[gb][24 + guu] + bf2f(zx_o);
    float ig = 1.f / (1.f + __expf(-zi));
    float fg = 1.f / (1.f + __expf(-zf));
    float gg = tanhf(zg);
    float og = 1.f / (1.f + __expf(-zo));
    float cn = fg * cst[gb][guu] + ig * gg;
    cst[gb][guu] = cn;
    float hn = og * tanhf(cn);
    hring[((size_t)t * BATCH + gb) * UNITS + u0 + guu] = f2bf(hn);
    __syncthreads();   // all hring stores ack'd (vmcnt drained per-thread)
    if (tid == 0)
      __hip_atomic_fetch_add(&done[t], 1, __ATOMIC_RELEASE, __HIP_MEMORY_SCOPE_AGENT);

    // out writes off the release critical path; nontemporal -> no dirty L2
    int sidx = dir ? (SEQ - 1 - t) : t;
    __builtin_nontemporal_store(hn, &out[((size_t)gb * SEQ + sidx) * 1024 + dir * 512 + u0 + guu]);
    if (t == SEQ - 1) {
      size_t base = (size_t)BATCH * SEQ * 1024;
      __builtin_nontemporal_store(hn, &out[base + (size_t)(2*dir  ) * BATCH * UNITS + (size_t)gb * UNITS + u0 + guu]);
      __builtin_nontemporal_store(cn, &out[base + (size_t)(2*dir+1) * BATCH * UNITS + (size_t)gb * UNITS + u0 + guu]);
    }
  }
}

// -------------------- launch ----------------------------------------------
extern "C" void kernel_launch(void* const* d_in, const int* in_sizes, int n_in,
                              void* d_out, int out_size, void* d_ws, size_t ws_size,
                              hipStream_t stream)
{
  const int*   x   = (const int*)  d_in[0];
  const float* fh  = (const float*)d_in[1];
  const float* fc  = (const float*)d_in[2];
  const float* bh  = (const float*)d_in[3];
  const float* bc  = (const float*)d_in[4];
  const float* emb = (const float*)d_in[5];
  const float* Wf  = (const float*)d_in[6];
  const float* Uf  = (const float*)d_in[7];
  const float* bf  = (const float*)d_in[8];
  const float* Wb  = (const float*)d_in[9];
  const float* Ub  = (const float*)d_in[10];
  const float* bb  = (const float*)d_in[11];
  float* out = (float*)d_out;

  if (ws_size < FLG_OFF + FLG_BYTES) return;

  unsigned short* zx2   = (unsigned short*)((char*)d_ws + ZX2_OFF);
  unsigned short* hring = (unsigned short*)((char*)d_ws + HB_OFF);
  int*            flags = (int*)((char*)d_ws + FLG_OFF);

  hipMemsetAsync(flags, 0, FLG_BYTES, stream);
  k_zx  <<<dim3(32, 256, 2), 256, 0, stream>>>(x, emb, Wf, bf, Wb, bb, zx2);
  k_rec2<<<dim3(128),        256, 0, stream>>>(fh, fc, bh, bc, Uf, Ub, zx2, hring, flags, out);
}

// Round 4
// 3298.717 us; speedup vs baseline: 10.0862x; 1.4280x over previous
//
#include <hip/hip_runtime.h>

#define SEQ   512
#define BATCH 32
#define EMBD  256
#define UNITS 512
#define G4    2048   // 4*UNITS
#define NW1   128    // K1 zx slot count (units/4)
#define NW2   64     // K2 workgroups per direction
#define UPW   8      // units per K2 workgroup
#define HSTR  520    // LDS h row stride in shorts (512 + 8 => +1 bank quad)

typedef short  short8 __attribute__((ext_vector_type(8)));
typedef float  f32x4  __attribute__((ext_vector_type(4)));
typedef unsigned int u32x4 __attribute__((ext_vector_type(4)));

static constexpr unsigned long long ZX2_OFF   = 0ull;
static constexpr unsigned long long ZX2_BYTES = 2ull * SEQ * NW1 * BATCH * 16 * 2; // 128 MiB
static constexpr unsigned long long HB_OFF    = ZX2_OFF + ZX2_BYTES;
static constexpr unsigned long long HB_BYTES  = 2ull * SEQ * BATCH * UNITS * 2;    // 32 MiB bf16

__device__ __forceinline__ unsigned short f2bf(float f) {
  unsigned int u = __float_as_uint(f);
  u = (u + 0x7FFFu + ((u >> 16) & 1u)) >> 16;
  return (unsigned short)u;
}
__device__ __forceinline__ float bf2f(unsigned short s) {
  return __uint_as_float(((unsigned int)s) << 16);
}
// sentinel = 0xFFFF (bf16 NaN). h = sigmoid*tanh, |h|<1 => never NaN pattern.
__device__ __forceinline__ unsigned sent2(unsigned w) {
  return (unsigned)(((w & 0xFFFFu) == 0xFFFFu) | ((w >> 16) == 0xFFFFu));
}
__device__ __forceinline__ float fast_tanh(float x) {
  x = fminf(15.f, fmaxf(-15.f, x));
  float e = __expf(2.f * x);
  return (e - 1.f) / (e + 1.f);
}

// -------------------- K1: zx = gather(emb,x) @ W + b  (fp32, bf16 out) -----
// unchanged (verified rounds 1-3)
__global__ __launch_bounds__(256)
void k_zx(const int* __restrict__ x, const float* __restrict__ emb,
          const float* __restrict__ Wf, const float* __restrict__ bf,
          const float* __restrict__ Wb, const float* __restrict__ bb,
          unsigned short* __restrict__ zx2)
{
  const int nb  = blockIdx.x;
  const int mb  = blockIdx.y;
  const int dir = blockIdx.z;
  const float* __restrict__ W    = dir ? Wb : Wf;
  const float* __restrict__ bias = dir ? bb : bf;
  const int tid = threadIdx.x;
  const int M0 = mb * 64, N0 = nb * 64;

  __shared__ __align__(16) float Ast[32][68];
  __shared__ __align__(16) float Bs [32][68];
  __shared__ int tok[64];

  if (tid < 64) {
    int m = M0 + tid;
    int t = m >> 5, b = m & 31;
    int s = dir ? (SEQ - 1 - t) : t;
    tok[tid] = x[b * SEQ + s];
  }

  float acc[4][4];
  #pragma unroll
  for (int r = 0; r < 4; ++r)
    #pragma unroll
    for (int c = 0; c < 4; ++c) acc[r][c] = 0.f;

  const int mq = tid >> 4, nq = tid & 15;

  for (int kb = 0; kb < 8; ++kb) {
    __syncthreads();
    {
      int m = tid >> 2, q = tid & 3;
      const float* src = emb + (size_t)tok[m] * EMBD + kb * 32 + q * 8;
      float4 v0 = *(const float4*)src;
      float4 v1 = *(const float4*)(src + 4);
      int k0 = q * 8;
      Ast[k0+0][m] = v0.x; Ast[k0+1][m] = v0.y; Ast[k0+2][m] = v0.z; Ast[k0+3][m] = v0.w;
      Ast[k0+4][m] = v1.x; Ast[k0+5][m] = v1.y; Ast[k0+6][m] = v1.z; Ast[k0+7][m] = v1.w;
    }
    {
      int k = tid >> 3, q = tid & 7;
      const float* src = W + (size_t)(kb*32 + k) * G4 + N0 + q * 8;
      float4 w0 = *(const float4*)src;
      float4 w1 = *(const float4*)(src + 4);
      *(float4*)&Bs[k][q*8]     = w0;
      *(float4*)&Bs[k][q*8 + 4] = w1;
    }
    __syncthreads();
    #pragma unroll 8
    for (int k = 0; k < 32; ++k) {
      float4 a  = *(const float4*)&Ast[k][mq*4];
      float4 bv = *(const float4*)&Bs[k][nq*4];
      acc[0][0] += a.x*bv.x; acc[0][1] += a.x*bv.y; acc[0][2] += a.x*bv.z; acc[0][3] += a.x*bv.w;
      acc[1][0] += a.y*bv.x; acc[1][1] += a.y*bv.y; acc[1][2] += a.y*bv.z; acc[1][3] += a.y*bv.w;
      acc[2][0] += a.z*bv.x; acc[2][1] += a.z*bv.y; acc[2][2] += a.z*bv.z; acc[2][3] += a.z*bv.w;
      acc[3][0] += a.w*bv.x; acc[3][1] += a.w*bv.y; acc[3][2] += a.w*bv.z; acc[3][3] += a.w*bv.w;
    }
  }

  float4 bs4 = *(const float4*)(bias + N0 + nq*4);
  const int g = N0 >> 9;
  const int u = (N0 & 511) + nq * 4;
  const int w = u >> 2;
  #pragma unroll
  for (int r = 0; r < 4; ++r) {
    int m = M0 + mq*4 + r;
    int t = m >> 5, b = m & 31;
    unsigned short p0 = f2bf(acc[r][0] + bs4.x);
    unsigned short p1 = f2bf(acc[r][1] + bs4.y);
    unsigned short p2 = f2bf(acc[r][2] + bs4.z);
    unsigned short p3 = f2bf(acc[r][3] + bs4.w);
    uint2 pk;
    pk.x = (unsigned)p0 | ((unsigned)p1 << 16);
    pk.y = (unsigned)p2 | ((unsigned)p3 << 16);
    size_t off = ((((size_t)dir*SEQ + t)*NW1 + w)*BATCH + b)*16 + g*4;
    *(uint2*)(zx2 + off) = pk;
  }
}

// -------------------- K2: recurrence, data-flow sentinel sync ---------------
__global__ __launch_bounds__(256, 1)
void k_rec2(const float* __restrict__ fh, const float* __restrict__ fc,
            const float* __restrict__ bh, const float* __restrict__ bc,
            const float* __restrict__ Uf, const float* __restrict__ Ub,
            const unsigned short* __restrict__ zx2,
            unsigned short* __restrict__ hring_all,
            float* __restrict__ out)
{
  const int bid = blockIdx.x;      // 0..127
  const int dir = bid >> 6;
  const int w   = bid & 63;
  const int u0  = w * UPW;
  const int tid = threadIdx.x;
  const int l   = tid & 63;
  const int wid = tid >> 6;
  const int mt  = wid & 1;         // M-tile (b 0..15 / 16..31)
  const int ct  = wid >> 1;        // col-tile (gates i,f / g,o)
  const float* __restrict__ U  = dir ? Ub : Uf;
  const float* __restrict__ h0 = dir ? bh : fh;
  const float* __restrict__ c0 = dir ? bc : fc;

  __shared__ __align__(16) unsigned short hs[BATCH * HSTR]; // [b][k] bf16, row pad
  __shared__ __align__(16) float zbuf[BATCH][33];
  __shared__ float cst[BATCH][9];

  unsigned short* __restrict__ hring = hring_all + (size_t)dir * SEQ * BATCH * UNITS;
  const unsigned short* __restrict__ zxd =
      zx2 + ((size_t)dir * SEQ) * (NW1 * BATCH * 16);

  // ---- preload U slice as bf16 MFMA B-fragments, hi/lo split ---------------
  const int colg = (l & 15) >> 3;
  const int krow = (l >> 4) * 8;
  const size_t gcol = (size_t)(ct * 2 + colg) * 512 + u0 + (l & 7);
  short8 uhi[16], ulo[16];
  #pragma unroll
  for (int s = 0; s < 16; ++s) {
    const float* up = U + (size_t)(s * 32 + krow) * G4 + gcol;
    short8 hi8, lo8;
    #pragma unroll
    for (int j = 0; j < 8; ++j) {
      float uv = up[(size_t)j * G4];
      unsigned short h16 = f2bf(uv);
      float rem = uv - bf2f(h16);
      hi8[j] = (short)h16;
      lo8[j] = (short)f2bf(rem);
    }
    uhi[s] = hi8; ulo[s] = lo8;
  }

  // ---- init cell state -------------------------------------------------------
  {
    int b = tid & 31, uu = tid >> 5;
    cst[b][uu] = c0[b * UNITS + u0 + uu];
  }

  // ---- stage h0 (fp32 -> bf16), padded rows ----------------------------------
  {
    int r = tid >> 3, c0q = tid & 7;
    const float* src = h0 + (size_t)r * UNITS;
    #pragma unroll
    for (int i = 0; i < 8; ++i) {
      int c = i * 8 + c0q;
      float4 v0 = *(const float4*)(src + c * 8);
      float4 v1 = *(const float4*)(src + c * 8 + 4);
      short8 pk;
      pk[0]=(short)f2bf(v0.x); pk[1]=(short)f2bf(v0.y);
      pk[2]=(short)f2bf(v0.z); pk[3]=(short)f2bf(v0.w);
      pk[4]=(short)f2bf(v1.x); pk[5]=(short)f2bf(v1.y);
      pk[6]=(short)f2bf(v1.z); pk[7]=(short)f2bf(v1.w);
      *(short8*)(&hs[r * HSTR + c * 8]) = pk;
    }
  }
  __syncthreads();

  // gate-phase mapping
  const int gb  = tid & 31;
  const int guu = tid >> 5;
  const int slot = 2 * w + (guu >> 2);
  const int zxi0 = (slot * BATCH + gb) * 16 + (guu & 3);
  // A-read per-lane constants
  const int arow  = 16 * mt + (l & 15);
  const unsigned short* hsrow = hs + arow * HSTR;
  const int agrp0 = l >> 4;
  // staging constants
  const int sr = tid >> 3, sc0q = tid & 7;
  unsigned short* const hs_dst = hs + sr * HSTR + sc0q * 8;

  for (int t = 0; t < SEQ; ++t) {
    // prefetch zx for this step (plain cached loads; zx2 static, L2 stays warm)
    const unsigned short* zxt = zxd + (size_t)t * (NW1 * BATCH * 16) + zxi0;
    unsigned short zx_i = zxt[0], zx_f = zxt[4], zx_g = zxt[8], zx_o = zxt[12];

    if (t > 0) {
      // ---- data-flow poll: coherent loads of h(t-1), sentinel retry --------
      const unsigned short* src =
          hring + ((size_t)(t - 1) * BATCH + sr) * UNITS + sc0q * 8;
      u32x4 g0, g1, g2, g3, g4, g5, g6, g7;
      int guard = 0;
      for (;;) {
        asm volatile(
          "global_load_dwordx4 %0, %8, off sc0 sc1\n\t"
          "global_load_dwordx4 %1, %8, off offset:128 sc0 sc1\n\t"
          "global_load_dwordx4 %2, %8, off offset:256 sc0 sc1\n\t"
          "global_load_dwordx4 %3, %8, off offset:384 sc0 sc1\n\t"
          "global_load_dwordx4 %4, %8, off offset:512 sc0 sc1\n\t"
          "global_load_dwordx4 %5, %8, off offset:640 sc0 sc1\n\t"
          "global_load_dwordx4 %6, %8, off offset:768 sc0 sc1\n\t"
          "global_load_dwordx4 %7, %8, off offset:896 sc0 sc1\n\t"
          "s_waitcnt vmcnt(0)"
          : "=&v"(g0), "=&v"(g1), "=&v"(g2), "=&v"(g3),
            "=&v"(g4), "=&v"(g5), "=&v"(g6), "=&v"(g7)
          : "v"(src)
          : "memory");
        __builtin_amdgcn_sched_barrier(0);
        unsigned bad = 0;
        #pragma unroll
        for (int j = 0; j < 4; ++j) {
          bad |= sent2(g0[j]) | sent2(g1[j]) | sent2(g2[j]) | sent2(g3[j])
               | sent2(g4[j]) | sent2(g5[j]) | sent2(g6[j]) | sent2(g7[j]);
        }
        if (!bad || ++guard >= (1 << 20)) break;
        __builtin_amdgcn_s_sleep(1);
      }
      // commit to LDS (groups i*8+sc0q -> short offset i*64)
      *(u32x4*)(hs_dst      ) = g0;
      *(u32x4*)(hs_dst +  64) = g1;
      *(u32x4*)(hs_dst + 128) = g2;
      *(u32x4*)(hs_dst + 192) = g3;
      *(u32x4*)(hs_dst + 256) = g4;
      *(u32x4*)(hs_dst + 320) = g5;
      *(u32x4*)(hs_dst + 384) = g6;
      *(u32x4*)(hs_dst + 448) = g7;
      __syncthreads();
    }

    // ---- z = h · (Uhi + Ulo) via MFMA ----
    f32x4 acc = {0.f, 0.f, 0.f, 0.f};
    #pragma unroll
    for (int s = 0; s < 16; ++s) {
      short8 a = *(const short8*)(hsrow + (4 * s + agrp0) * 8);
      acc = __builtin_amdgcn_mfma_f32_16x16x32_bf16(a, uhi[s], acc, 0, 0, 0);
      acc = __builtin_amdgcn_mfma_f32_16x16x32_bf16(a, ulo[s], acc, 0, 0, 0);
    }
    // C/D: col = lane&15, row = (lane>>4)*4 + reg  [verified layout]
    #pragma unroll
    for (int r = 0; r < 4; ++r)
      zbuf[16 * mt + (l >> 4) * 4 + r][ct * 16 + (l & 15)] = acc[r];
    __syncthreads();

    // ---- gates: thread = (gb, guu) ----
    float zi = zbuf[gb][     guu] + bf2f(zx_i);
    float zf = zbuf[gb][ 8 + guu] + bf2f(zx_f);
    float zg = zbuf[gb][16 + guu] + bf2f(zx_g);
    float zo = zbuf[gb][24 + guu] + bf2f(zx_o);
    float ig = 1.f / (1.f + __expf(-zi));
    float fg = 1.f / (1.f + __expf(-zf));
    float gg = fast_tanh(zg);
    float og = 1.f / (1.f + __expf(-zo));
    float cn = fg * cst[gb][guu] + ig * gg;
    cst[gb][guu] = cn;
    float hn = og * fast_tanh(cn);

    // publish h: write-through coherent 2B store (no fence, no flag)
    {
      unsigned hb = (unsigned)f2bf(hn);
      unsigned short* dst = hring + ((size_t)t * BATCH + gb) * UNITS + u0 + guu;
      asm volatile("global_store_short %0, %1, off sc0 sc1"
                   :: "v"(dst), "v"(hb) : "memory");
    }

    // out writes (not on the sync path)
    int sidx = dir ? (SEQ - 1 - t) : t;
    __builtin_nontemporal_store(hn, &out[((size_t)gb * SEQ + sidx) * 1024 + dir * 512 + u0 + guu]);
    if (t == SEQ - 1) {
      size_t base = (size_t)BATCH * SEQ * 1024;
      __builtin_nontemporal_store(hn, &out[base + (size_t)(2*dir  ) * BATCH * UNITS + (size_t)gb * UNITS + u0 + guu]);
      __builtin_nontemporal_store(cn, &out[base + (size_t)(2*dir+1) * BATCH * UNITS + (size_t)gb * UNITS + u0 + guu]);
    }
  }
}

// -------------------- launch ----------------------------------------------
extern "C" void kernel_launch(void* const* d_in, const int* in_sizes, int n_in,
                              void* d_out, int out_size, void* d_ws, size_t ws_size,
                              hipStream_t stream)
{
  const int*   x   = (const int*)  d_in[0];
  const float* fh  = (const float*)d_in[1];
  const float* fc  = (const float*)d_in[2];
  const float* bh  = (const float*)d_in[3];
  const float* bc  = (const float*)d_in[4];
  const float* emb = (const float*)d_in[5];
  const float* Wf  = (const float*)d_in[6];
  const float* Uf  = (const float*)d_in[7];
  const float* bf  = (const float*)d_in[8];
  const float* Wb  = (const float*)d_in[9];
  const float* Ub  = (const float*)d_in[10];
  const float* bb  = (const float*)d_in[11];
  float* out = (float*)d_out;

  if (ws_size < HB_OFF + HB_BYTES) return;

  unsigned short* zx2   = (unsigned short*)((char*)d_ws + ZX2_OFF);
  unsigned short* hring = (unsigned short*)((char*)d_ws + HB_OFF);

  // sentinel-fill the h ring every launch (0xFFFF bf16 NaN = "not ready")
  hipMemsetAsync(hring, 0xFF, HB_BYTES, stream);
  k_zx  <<<dim3(32, 256, 2), 256, 0, stream>>>(x, emb, Wf, bf, Wb, bb, zx2);
  k_rec2<<<dim3(128),        256, 0, stream>>>(fh, fc, bh, bc, Uf, Ub, zx2, hring, out);
}

// Round 5
// 2638.344 us; speedup vs baseline: 12.6108x; 1.2503x over previous
//
#include <hip/hip_runtime.h>

#define SEQ   512
#define BATCH 32
#define EMBD  256
#define UNITS 512
#define G4    2048   // 4*UNITS
#define NW1   128    // K1 zx slot count (units/4)
#define NW2   64     // K2 workgroups per direction
#define UPW   8      // units per K2 workgroup
#define HSTR  520    // LDS h row stride in shorts (512 + 8 => +1 bank quad)

typedef short  short8 __attribute__((ext_vector_type(8)));
typedef float  f32x4  __attribute__((ext_vector_type(4)));
typedef unsigned int u32x4 __attribute__((ext_vector_type(4)));
typedef unsigned int u32x2 __attribute__((ext_vector_type(2)));

static constexpr unsigned long long ZX2_OFF   = 0ull;
static constexpr unsigned long long ZX2_BYTES = 2ull * SEQ * NW1 * BATCH * 16 * 2; // 128 MiB
static constexpr unsigned long long HB_OFF    = ZX2_OFF + ZX2_BYTES;
static constexpr unsigned long long HB_BYTES  = 2ull * SEQ * BATCH * UNITS * 2;    // 32 MiB bf16

__device__ __forceinline__ unsigned short f2bf(float f) {
  unsigned int u = __float_as_uint(f);
  u = (u + 0x7FFFu + ((u >> 16) & 1u)) >> 16;
  return (unsigned short)u;
}
__device__ __forceinline__ float bf2f(unsigned short s) {
  return __uint_as_float(((unsigned int)s) << 16);
}
// sentinel = 0xFFFF (bf16 NaN). h = sigmoid*tanh, |h|<1 => never NaN pattern.
__device__ __forceinline__ unsigned sent2(unsigned w) {
  return (unsigned)(((w & 0xFFFFu) == 0xFFFFu) | ((w >> 16) == 0xFFFFu));
}
__device__ __forceinline__ unsigned chk4(u32x4 g) {
  return sent2(g[0]) | sent2(g[1]) | sent2(g[2]) | sent2(g[3]);
}

// -------------------- K1: zx = gather(emb,x) @ W + b  (fp32, bf16 out) -----
// unchanged (verified rounds 1-4)
__global__ __launch_bounds__(256)
void k_zx(const int* __restrict__ x, const float* __restrict__ emb,
          const float* __restrict__ Wf, const float* __restrict__ bf,
          const float* __restrict__ Wb, const float* __restrict__ bb,
          unsigned short* __restrict__ zx2)
{
  const int nb  = blockIdx.x;
  const int mb  = blockIdx.y;
  const int dir = blockIdx.z;
  const float* __restrict__ W    = dir ? Wb : Wf;
  const float* __restrict__ bias = dir ? bb : bf;
  const int tid = threadIdx.x;
  const int M0 = mb * 64, N0 = nb * 64;

  __shared__ __align__(16) float Ast[32][68];
  __shared__ __align__(16) float Bs [32][68];
  __shared__ int tok[64];

  if (tid < 64) {
    int m = M0 + tid;
    int t = m >> 5, b = m & 31;
    int s = dir ? (SEQ - 1 - t) : t;
    tok[tid] = x[b * SEQ + s];
  }

  float acc[4][4];
  #pragma unroll
  for (int r = 0; r < 4; ++r)
    #pragma unroll
    for (int c = 0; c < 4; ++c) acc[r][c] = 0.f;

  const int mq = tid >> 4, nq = tid & 15;

  for (int kb = 0; kb < 8; ++kb) {
    __syncthreads();
    {
      int m = tid >> 2, q = tid & 3;
      const float* src = emb + (size_t)tok[m] * EMBD + kb * 32 + q * 8;
      float4 v0 = *(const float4*)src;
      float4 v1 = *(const float4*)(src + 4);
      int k0 = q * 8;
      Ast[k0+0][m] = v0.x; Ast[k0+1][m] = v0.y; Ast[k0+2][m] = v0.z; Ast[k0+3][m] = v0.w;
      Ast[k0+4][m] = v1.x; Ast[k0+5][m] = v1.y; Ast[k0+6][m] = v1.z; Ast[k0+7][m] = v1.w;
    }
    {
      int k = tid >> 3, q = tid & 7;
      const float* src = W + (size_t)(kb*32 + k) * G4 + N0 + q * 8;
      float4 w0 = *(const float4*)src;
      float4 w1 = *(const float4*)(src + 4);
      *(float4*)&Bs[k][q*8]     = w0;
      *(float4*)&Bs[k][q*8 + 4] = w1;
    }
    __syncthreads();
    #pragma unroll 8
    for (int k = 0; k < 32; ++k) {
      float4 a  = *(const float4*)&Ast[k][mq*4];
      float4 bv = *(const float4*)&Bs[k][nq*4];
      acc[0][0] += a.x*bv.x; acc[0][1] += a.x*bv.y; acc[0][2] += a.x*bv.z; acc[0][3] += a.x*bv.w;
      acc[1][0] += a.y*bv.x; acc[1][1] += a.y*bv.y; acc[1][2] += a.y*bv.z; acc[1][3] += a.y*bv.w;
      acc[2][0] += a.z*bv.x; acc[2][1] += a.z*bv.y; acc[2][2] += a.z*bv.z; acc[2][3] += a.z*bv.w;
      acc[3][0] += a.w*bv.x; acc[3][1] += a.w*bv.y; acc[3][2] += a.w*bv.z; acc[3][3] += a.w*bv.w;
    }
  }

  float4 bs4 = *(const float4*)(bias + N0 + nq*4);
  const int g = N0 >> 9;
  const int u = (N0 & 511) + nq * 4;
  const int w = u >> 2;
  #pragma unroll
  for (int r = 0; r < 4; ++r) {
    int m = M0 + mq*4 + r;
    int t = m >> 5, b = m & 31;
    unsigned short p0 = f2bf(acc[r][0] + bs4.x);
    unsigned short p1 = f2bf(acc[r][1] + bs4.y);
    unsigned short p2 = f2bf(acc[r][2] + bs4.z);
    unsigned short p3 = f2bf(acc[r][3] + bs4.w);
    uint2 pk;
    pk.x = (unsigned)p0 | ((unsigned)p1 << 16);
    pk.y = (unsigned)p2 | ((unsigned)p3 << 16);
    size_t off = ((((size_t)dir*SEQ + t)*NW1 + w)*BATCH + b)*16 + g*4;
    *(uint2*)(zx2 + off) = pk;
  }
}

// -------------------- K2: recurrence, in-register gates + straggler retry ---
// wave tiling: 16 cols = 4 gates x 4 units. col c: gate=(c>>2), unit=ct*4+(c&3)
__global__ __launch_bounds__(256, 1)
void k_rec2(const float* __restrict__ fh, const float* __restrict__ fc,
            const float* __restrict__ bh, const float* __restrict__ bc,
            const float* __restrict__ Uf, const float* __restrict__ Ub,
            const unsigned short* __restrict__ zx2,
            unsigned short* __restrict__ hring_all,
            float* __restrict__ out)
{
  const int bid = blockIdx.x;      // 0..127
  const int dir = bid >> 6;
  const int w   = bid & 63;
  const int u0  = w * UPW;
  const int tid = threadIdx.x;
  const int l   = tid & 63;
  const int wid = tid >> 6;
  const int mt  = wid & 1;         // M-tile (b 0..15 / 16..31)
  const int ct  = wid >> 1;        // unit-pair tile (units 0..3 / 4..7)
  const float* __restrict__ U  = dir ? Ub : Uf;
  const float* __restrict__ h0 = dir ? bh : fh;
  const float* __restrict__ c0 = dir ? bc : fc;

  __shared__ __align__(16) unsigned short hs[BATCH * HSTR]; // [b][k] bf16, row pad

  unsigned short* __restrict__ hring = hring_all + (size_t)dir * SEQ * BATCH * UNITS;
  const unsigned short* __restrict__ zxd =
      zx2 + ((size_t)dir * SEQ) * (NW1 * BATCH * 16);

  // ---- preload U slice as bf16 MFMA B-fragments, hi/lo split ---------------
  // B layout (16x16x32): lane l holds col=l&15, k=(l>>4)*8+j.
  // col -> gate (l&15)>>2, unit u0 + ct*4 + (l&3)
  const int krow = (l >> 4) * 8;
  const size_t gcol = (size_t)((l & 15) >> 2) * 512 + u0 + ct * 4 + (l & 3);
  short8 uhi[16], ulo[16];
  #pragma unroll
  for (int s = 0; s < 16; ++s) {
    const float* up = U + (size_t)(s * 32 + krow) * G4 + gcol;
    short8 hi8, lo8;
    #pragma unroll
    for (int j = 0; j < 8; ++j) {
      float uv = up[(size_t)j * G4];
      unsigned short h16 = f2bf(uv);
      float rem = uv - bf2f(h16);
      hi8[j] = (short)h16;
      lo8[j] = (short)f2bf(rem);
    }
    uhi[s] = hi8; ulo[s] = lo8;
  }

  // ---- per-lane cell state (valid on gate-0 lanes; benign elsewhere) -------
  float c_old[4];
  #pragma unroll
  for (int r = 0; r < 4; ++r) {
    int b_r = 16 * mt + (l >> 4) * 4 + r;
    c_old[r] = c0[(size_t)b_r * UNITS + u0 + ct * 4 + (l & 3)];
  }

  // ---- stage h0 (fp32 -> bf16), padded rows ---------------------------------
  {
    int r = tid >> 3, c0q = tid & 7;
    const float* src = h0 + (size_t)r * UNITS;
    #pragma unroll
    for (int i = 0; i < 8; ++i) {
      int c = i * 8 + c0q;
      float4 v0 = *(const float4*)(src + c * 8);
      float4 v1 = *(const float4*)(src + c * 8 + 4);
      short8 pk;
      pk[0]=(short)f2bf(v0.x); pk[1]=(short)f2bf(v0.y);
      pk[2]=(short)f2bf(v0.z); pk[3]=(short)f2bf(v0.w);
      pk[4]=(short)f2bf(v1.x); pk[5]=(short)f2bf(v1.y);
      pk[6]=(short)f2bf(v1.z); pk[7]=(short)f2bf(v1.w);
      *(short8*)(&hs[r * HSTR + c * 8]) = pk;
    }
  }
  __syncthreads();

  // per-lane constants
  const int arow  = 16 * mt + (l & 15);
  const unsigned short* hsrow = hs + arow * HSTR;
  const int agrp0 = l >> 4;
  const int sr = tid >> 3, sc0q = tid & 7;
  unsigned short* const hs_dst = hs + sr * HSTR + sc0q * 8;
  const bool isg = ((l & 15) >> 2) == 2;           // gate 2 = tanh
  const float An = isg ? 2.f : 1.f;
  const float Cn = isg ? -1.f : 0.f;
  const float Bn = isg ? -2.f : -1.f;
  const size_t ZXT = (size_t)NW1 * BATCH * 16;
  const size_t zbase = ((size_t)(2 * w + ct) * BATCH + 16 * mt + (l >> 4) * 4) * 16
                       + ((l & 15) >> 2) * 4 + (l & 3);

  for (int t = 0; t < SEQ; ++t) {
    // prefetch zx for this step (plain cached; zx2 deterministic across replays)
    unsigned short zxr[4];
    #pragma unroll
    for (int r = 0; r < 4; ++r) zxr[r] = zxd[(size_t)t * ZXT + zbase + r * 16];

    if (t > 0) {
      // ---- data-flow poll: burst fetch, then straggler-only retries --------
      const unsigned short* src =
          hring + ((size_t)(t - 1) * BATCH + sr) * UNITS + sc0q * 8;
      u32x4 g0, g1, g2, g3, g4, g5, g6, g7;
      asm volatile("global_load_dwordx4 %0, %1, off sc0 sc1"            : "=&v"(g0) : "v"(src) : "memory");
      asm volatile("global_load_dwordx4 %0, %1, off offset:128 sc0 sc1" : "=&v"(g1) : "v"(src) : "memory");
      asm volatile("global_load_dwordx4 %0, %1, off offset:256 sc0 sc1" : "=&v"(g2) : "v"(src) : "memory");
      asm volatile("global_load_dwordx4 %0, %1, off offset:384 sc0 sc1" : "=&v"(g3) : "v"(src) : "memory");
      asm volatile("global_load_dwordx4 %0, %1, off offset:512 sc0 sc1" : "=&v"(g4) : "v"(src) : "memory");
      asm volatile("global_load_dwordx4 %0, %1, off offset:640 sc0 sc1" : "=&v"(g5) : "v"(src) : "memory");
      asm volatile("global_load_dwordx4 %0, %1, off offset:768 sc0 sc1" : "=&v"(g6) : "v"(src) : "memory");
      asm volatile("global_load_dwordx4 %0, %1, off offset:896 sc0 sc1" : "=&v"(g7) : "v"(src) : "memory");
      asm volatile("s_waitcnt vmcnt(0)"
                   : "+v"(g0), "+v"(g1), "+v"(g2), "+v"(g3),
                     "+v"(g4), "+v"(g5), "+v"(g6), "+v"(g7));
      __builtin_amdgcn_sched_barrier(0);
      unsigned b0 = chk4(g0), b1 = chk4(g1), b2 = chk4(g2), b3 = chk4(g3);
      unsigned b4 = chk4(g4), b5 = chk4(g5), b6 = chk4(g6), b7 = chk4(g7);
      int guard = 0;
      while ((b0 | b1 | b2 | b3 | b4 | b5 | b6 | b7) && ++guard < (1 << 20)) {
        __builtin_amdgcn_s_sleep(1);
        if (b0) asm volatile("global_load_dwordx4 %0, %1, off sc0 sc1"            : "=&v"(g0) : "v"(src) : "memory");
        if (b1) asm volatile("global_load_dwordx4 %0, %1, off offset:128 sc0 sc1" : "=&v"(g1) : "v"(src) : "memory");
        if (b2) asm volatile("global_load_dwordx4 %0, %1, off offset:256 sc0 sc1" : "=&v"(g2) : "v"(src) : "memory");
        if (b3) asm volatile("global_load_dwordx4 %0, %1, off offset:384 sc0 sc1" : "=&v"(g3) : "v"(src) : "memory");
        if (b4) asm volatile("global_load_dwordx4 %0, %1, off offset:512 sc0 sc1" : "=&v"(g4) : "v"(src) : "memory");
        if (b5) asm volatile("global_load_dwordx4 %0, %1, off offset:640 sc0 sc1" : "=&v"(g5) : "v"(src) : "memory");
        if (b6) asm volatile("global_load_dwordx4 %0, %1, off offset:768 sc0 sc1" : "=&v"(g6) : "v"(src) : "memory");
        if (b7) asm volatile("global_load_dwordx4 %0, %1, off offset:896 sc0 sc1" : "=&v"(g7) : "v"(src) : "memory");
        asm volatile("s_waitcnt vmcnt(0)"
                     : "+v"(g0), "+v"(g1), "+v"(g2), "+v"(g3),
                       "+v"(g4), "+v"(g5), "+v"(g6), "+v"(g7));
        __builtin_amdgcn_sched_barrier(0);
        b0 = chk4(g0); b1 = chk4(g1); b2 = chk4(g2); b3 = chk4(g3);
        b4 = chk4(g4); b5 = chk4(g5); b6 = chk4(g6); b7 = chk4(g7);
      }
      // commit to LDS
      *(u32x4*)(hs_dst      ) = g0;
      *(u32x4*)(hs_dst +  64) = g1;
      *(u32x4*)(hs_dst + 128) = g2;
      *(u32x4*)(hs_dst + 192) = g3;
      *(u32x4*)(hs_dst + 256) = g4;
      *(u32x4*)(hs_dst + 320) = g5;
      *(u32x4*)(hs_dst + 384) = g6;
      *(u32x4*)(hs_dst + 448) = g7;
      __syncthreads();
    }

    // ---- z = h · (Uhi + Ulo) via MFMA, split accumulators ----
    f32x4 accA = {0.f, 0.f, 0.f, 0.f};
    f32x4 accB = {0.f, 0.f, 0.f, 0.f};
    #pragma unroll
    for (int s = 0; s < 16; ++s) {
      short8 a = *(const short8*)(hsrow + (4 * s + agrp0) * 8);
      accA = __builtin_amdgcn_mfma_f32_16x16x32_bf16(a, uhi[s], accA, 0, 0, 0);
      accB = __builtin_amdgcn_mfma_f32_16x16x32_bf16(a, ulo[s], accB, 0, 0, 0);
    }

    // ---- in-register gates: lanes l, l^4, l^8 hold the 4 gates of (b,u) ----
    // C/D: col = lane&15, row = (lane>>4)*4 + r  [verified layout]
    float vv[4];
    #pragma unroll
    for (int r = 0; r < 4; ++r) {
      float z = accA[r] + accB[r] + bf2f(zxr[r]);
      float e = __expf(Bn * z);
      vv[r] = An * __builtin_amdgcn_rcpf(1.f + e) + Cn;   // sigma or tanh
    }
    float hn[4], cn[4];
    unsigned pk0[4], pk1[4];
    #pragma unroll
    for (int r = 0; r < 4; ++r) {
      float wv = __shfl_xor(vv[r], 8);    // gate0 lane <- tanh(g) ; gate1 <- sig(o)
      float x1 = __shfl_xor(vv[r], 4);    // gate0 lane <- sig(f)
      float x2 = __shfl_xor(wv,    4);    // gate0 lane <- sig(o)
      cn[r] = x1 * c_old[r] + vv[r] * wv;
      c_old[r] = cn[r];
      float e2 = __expf(-2.f * cn[r]);
      float th = 2.f * __builtin_amdgcn_rcpf(1.f + e2) - 1.f;
      hn[r] = x2 * th;
      // pack 4 units (lanes l..l+3 within gate-0 group) into 2 dwords
      unsigned hb = (unsigned)f2bf(hn[r]);
      unsigned d  = (hb & 0xFFFFu) | (__shfl_xor((int)hb, 1) << 16);
      unsigned d2 = (unsigned)__shfl_xor((int)d, 2);
      pk0[r] = d; pk1[r] = d2;
    }

    // publish h: packed 8B write-through coherent stores (lane l&15==0 only)
    if ((l & 15) == 0) {
      #pragma unroll
      for (int r = 0; r < 4; ++r) {
        int b_r = 16 * mt + (l >> 4) * 4 + r;
        unsigned short* dst = hring + ((size_t)t * BATCH + b_r) * UNITS + u0 + ct * 4;
        u32x2 pk; pk[0] = pk0[r]; pk[1] = pk1[r];
        asm volatile("global_store_dwordx2 %0, %1, off sc0 sc1"
                     :: "v"(dst), "v"(pk) : "memory");
      }
    }

    // out writes (off the sync path), gate-0 lanes
    if ((l & 15) < 4) {
      int sidx = dir ? (SEQ - 1 - t) : t;
      #pragma unroll
      for (int r = 0; r < 4; ++r) {
        int b_r = 16 * mt + (l >> 4) * 4 + r;
        size_t oi = ((size_t)b_r * SEQ + sidx) * 1024 + dir * 512 + u0 + ct * 4 + (l & 3);
        __builtin_nontemporal_store(hn[r], &out[oi]);
      }
      if (t == SEQ - 1) {
        size_t base = (size_t)BATCH * SEQ * 1024;
        #pragma unroll
        for (int r = 0; r < 4; ++r) {
          int b_r = 16 * mt + (l >> 4) * 4 + r;
          size_t o1 = base + (size_t)(2*dir  ) * BATCH * UNITS + (size_t)b_r * UNITS + u0 + ct * 4 + (l & 3);
          size_t o2 = base + (size_t)(2*dir+1) * BATCH * UNITS + (size_t)b_r * UNITS + u0 + ct * 4 + (l & 3);
          __builtin_nontemporal_store(hn[r], &out[o1]);
          __builtin_nontemporal_store(cn[r], &out[o2]);
        }
      }
    }
  }
}

// -------------------- launch ----------------------------------------------
extern "C" void kernel_launch(void* const* d_in, const int* in_sizes, int n_in,
                              void* d_out, int out_size, void* d_ws, size_t ws_size,
                              hipStream_t stream)
{
  const int*   x   = (const int*)  d_in[0];
  const float* fh  = (const float*)d_in[1];
  const float* fc  = (const float*)d_in[2];
  const float* bh  = (const float*)d_in[3];
  const float* bc  = (const float*)d_in[4];
  const float* emb = (const float*)d_in[5];
  const float* Wf  = (const float*)d_in[6];
  const float* Uf  = (const float*)d_in[7];
  const float* bf  = (const float*)d_in[8];
  const float* Wb  = (const float*)d_in[9];
  const float* Ub  = (const float*)d_in[10];
  const float* bb  = (const float*)d_in[11];
  float* out = (float*)d_out;

  if (ws_size < HB_OFF + HB_BYTES) return;

  unsigned short* zx2   = (unsigned short*)((char*)d_ws + ZX2_OFF);
  unsigned short* hring = (unsigned short*)((char*)d_ws + HB_OFF);

  // sentinel-fill the h ring every launch (0xFFFF bf16 NaN = "not ready")
  hipMemsetAsync(hring, 0xFF, HB_BYTES, stream);
  k_zx  <<<dim3(32, 256, 2), 256, 0, stream>>>(x, emb, Wf, bf, Wb, bb, zx2);
  k_rec2<<<dim3(128),        256, 0, stream>>>(fh, fc, bh, bc, Uf, Ub, zx2, hring, out);
}

// Round 6
// 2060.968 us; speedup vs baseline: 16.1437x; 1.2801x over previous
//
#include <hip/hip_runtime.h>

#define SEQ   512
#define BATCH 32
#define EMBD  256
#define UNITS 512
#define G4    2048   // 4*UNITS
#define NW1   128    // K1 zx slot count (units/4), layout unchanged
#define NW2   32     // K2 workgroups per direction
#define UPW   16     // units per K2 workgroup
#define HSTR  520    // LDS h row stride in shorts (512 + 8 => +1 bank quad)
#define NTHR  512

typedef short  short8 __attribute__((ext_vector_type(8)));
typedef float  f32x4  __attribute__((ext_vector_type(4)));
typedef unsigned int u32x4 __attribute__((ext_vector_type(4)));
typedef unsigned int u32x2 __attribute__((ext_vector_type(2)));

static constexpr unsigned long long ZX2_OFF   = 0ull;
static constexpr unsigned long long ZX2_BYTES = 2ull * SEQ * NW1 * BATCH * 16 * 2; // 128 MiB
static constexpr unsigned long long HB_OFF    = ZX2_OFF + ZX2_BYTES;
static constexpr unsigned long long HB_BYTES  = 2ull * SEQ * BATCH * UNITS * 2;    // 32 MiB bf16
static constexpr unsigned long long FLG_OFF   = HB_OFF + HB_BYTES;
static constexpr unsigned long long FLG_BYTES = 2ull * NW2 * 4;                    // claim flags

__device__ __forceinline__ unsigned short f2bf(float f) {
  unsigned int u = __float_as_uint(f);
  u = (u + 0x7FFFu + ((u >> 16) & 1u)) >> 16;
  return (unsigned short)u;
}
__device__ __forceinline__ float bf2f(unsigned short s) {
  return __uint_as_float(((unsigned int)s) << 16);
}
// sentinel = 0xFFFF (bf16 NaN). h = sigmoid*tanh, |h|<1 => never NaN pattern.
__device__ __forceinline__ unsigned sent2(unsigned w) {
  return (unsigned)(((w & 0xFFFFu) == 0xFFFFu) | ((w >> 16) == 0xFFFFu));
}
__device__ __forceinline__ unsigned chk4(u32x4 g) {
  return sent2(g[0]) | sent2(g[1]) | sent2(g[2]) | sent2(g[3]);
}

// -------------------- K1: zx = gather(emb,x) @ W + b  (fp32, bf16 out) -----
// unchanged (verified rounds 1-5)
__global__ __launch_bounds__(256)
void k_zx(const int* __restrict__ x, const float* __restrict__ emb,
          const float* __restrict__ Wf, const float* __restrict__ bf,
          const float* __restrict__ Wb, const float* __restrict__ bb,
          unsigned short* __restrict__ zx2)
{
  const int nb  = blockIdx.x;
  const int mb  = blockIdx.y;
  const int dir = blockIdx.z;
  const float* __restrict__ W    = dir ? Wb : Wf;
  const float* __restrict__ bias = dir ? bb : bf;
  const int tid = threadIdx.x;
  const int M0 = mb * 64, N0 = nb * 64;

  __shared__ __align__(16) float Ast[32][68];
  __shared__ __align__(16) float Bs [32][68];
  __shared__ int tok[64];

  if (tid < 64) {
    int m = M0 + tid;
    int t = m >> 5, b = m & 31;
    int s = dir ? (SEQ - 1 - t) : t;
    tok[tid] = x[b * SEQ + s];
  }

  float acc[4][4];
  #pragma unroll
  for (int r = 0; r < 4; ++r)
    #pragma unroll
    for (int c = 0; c < 4; ++c) acc[r][c] = 0.f;

  const int mq = tid >> 4, nq = tid & 15;

  for (int kb = 0; kb < 8; ++kb) {
    __syncthreads();
    {
      int m = tid >> 2, q = tid & 3;
      const float* src = emb + (size_t)tok[m] * EMBD + kb * 32 + q * 8;
      float4 v0 = *(const float4*)src;
      float4 v1 = *(const float4*)(src + 4);
      int k0 = q * 8;
      Ast[k0+0][m] = v0.x; Ast[k0+1][m] = v0.y; Ast[k0+2][m] = v0.z; Ast[k0+3][m] = v0.w;
      Ast[k0+4][m] = v1.x; Ast[k0+5][m] = v1.y; Ast[k0+6][m] = v1.z; Ast[k0+7][m] = v1.w;
    }
    {
      int k = tid >> 3, q = tid & 7;
      const float* src = W + (size_t)(kb*32 + k) * G4 + N0 + q * 8;
      float4 w0 = *(const float4*)src;
      float4 w1 = *(const float4*)(src + 4);
      *(float4*)&Bs[k][q*8]     = w0;
      *(float4*)&Bs[k][q*8 + 4] = w1;
    }
    __syncthreads();
    #pragma unroll 8
    for (int k = 0; k < 32; ++k) {
      float4 a  = *(const float4*)&Ast[k][mq*4];
      float4 bv = *(const float4*)&Bs[k][nq*4];
      acc[0][0] += a.x*bv.x; acc[0][1] += a.x*bv.y; acc[0][2] += a.x*bv.z; acc[0][3] += a.x*bv.w;
      acc[1][0] += a.y*bv.x; acc[1][1] += a.y*bv.y; acc[1][2] += a.y*bv.z; acc[1][3] += a.y*bv.w;
      acc[2][0] += a.z*bv.x; acc[2][1] += a.z*bv.y; acc[2][2] += a.z*bv.z; acc[2][3] += a.z*bv.w;
      acc[3][0] += a.w*bv.x; acc[3][1] += a.w*bv.y; acc[3][2] += a.w*bv.z; acc[3][3] += a.w*bv.w;
    }
  }

  float4 bs4 = *(const float4*)(bias + N0 + nq*4);
  const int g = N0 >> 9;
  const int u = (N0 & 511) + nq * 4;
  const int w = u >> 2;
  #pragma unroll
  for (int r = 0; r < 4; ++r) {
    int m = M0 + mq*4 + r;
    int t = m >> 5, b = m & 31;
    unsigned short p0 = f2bf(acc[r][0] + bs4.x);
    unsigned short p1 = f2bf(acc[r][1] + bs4.y);
    unsigned short p2 = f2bf(acc[r][2] + bs4.z);
    unsigned short p3 = f2bf(acc[r][3] + bs4.w);
    uint2 pk;
    pk.x = (unsigned)p0 | ((unsigned)p1 << 16);
    pk.y = (unsigned)p2 | ((unsigned)p3 << 16);
    size_t off = ((((size_t)dir*SEQ + t)*NW1 + w)*BATCH + b)*16 + g*4;
    *(uint2*)(zx2 + off) = pk;
  }
}

// -------------------- K2: recurrence, XCD-local exchange --------------------
// 512 threads = 8 waves: mt = wid&1 (row half), ct = wid>>1 (unit quad 0..3)
__global__ __launch_bounds__(NTHR, 2)
void k_rec2(const float* __restrict__ fh, const float* __restrict__ fc,
            const float* __restrict__ bh, const float* __restrict__ bc,
            const float* __restrict__ Uf, const float* __restrict__ Ub,
            const unsigned short* __restrict__ zx2,
            unsigned short* __restrict__ hring_all,
            int* __restrict__ claim,
            float* __restrict__ out)
{
  const int tid = threadIdx.x;
  __shared__ int s_slot, s_loc;

  // ---- self-placement: claim a (dir,w) slot preferring the dir's home XCD --
  if (tid == 0) {
    unsigned xcc;
    asm volatile("s_getreg_b32 %0, hwreg(HW_REG_XCC_ID)" : "=s"(xcc));
    int slot = -1;
    if (xcc < 2) {
      int base = (int)xcc * NW2;
      for (int i = 0; i < NW2 && slot < 0; ++i)
        if (atomicCAS(&claim[base + i], 0, 1) == 0) slot = base + i;
    }
    if (slot < 0) {
      // let locals claim first (~20 us), then steal any leftover slot
      for (int sp = 0; sp < 96; ++sp) __builtin_amdgcn_s_sleep(8);
      for (int i = 0; i < 2 * NW2 && slot < 0; ++i)
        if (atomicCAS(&claim[i], 0, 1) == 0) slot = i;
    }
    s_slot = slot;
    s_loc  = (slot >= 0 && (unsigned)(slot >> 5) == xcc) ? 1 : 0;
  }
  __syncthreads();
  const int slot = s_slot;
  if (slot < 0) return;            // not a worker
  const int loc = s_loc;           // exchange partners on home XCD?
  const int dir = slot >> 5;
  const int w   = slot & (NW2 - 1);
  const int u0  = w * UPW;
  const int l   = tid & 63;
  const int wid = tid >> 6;
  const int mt  = wid & 1;         // row half (b 0..15 / 16..31)
  const int ct  = wid >> 1;        // unit quad 0..3

  const float* __restrict__ U  = dir ? Ub : Uf;
  const float* __restrict__ h0 = dir ? bh : fh;
  const float* __restrict__ c0 = dir ? bc : fc;

  __shared__ __align__(16) unsigned short hs[BATCH * HSTR];

  unsigned short* __restrict__ hring = hring_all + (size_t)dir * SEQ * BATCH * UNITS;
  const unsigned short* __restrict__ zxd =
      zx2 + ((size_t)dir * SEQ) * (NW1 * BATCH * 16);

  // ---- preload U slice as bf16 MFMA B-fragments, hi/lo split ---------------
  // B layout (16x16x32): lane l holds col=l&15, k=(l>>4)*8+j.
  // col -> gate (l&15)>>2, unit u0 + ct*4 + (l&3)
  const int krow = (l >> 4) * 8;
  const size_t gcol = (size_t)((l & 15) >> 2) * 512 + u0 + ct * 4 + (l & 3);
  short8 uhi[16], ulo[16];
  #pragma unroll
  for (int s = 0; s < 16; ++s) {
    const float* up = U + (size_t)(s * 32 + krow) * G4 + gcol;
    short8 hi8, lo8;
    #pragma unroll
    for (int j = 0; j < 8; ++j) {
      float uv = up[(size_t)j * G4];
      unsigned short h16 = f2bf(uv);
      float rem = uv - bf2f(h16);
      hi8[j] = (short)h16;
      lo8[j] = (short)f2bf(rem);
    }
    uhi[s] = hi8; ulo[s] = lo8;
  }

  // ---- per-lane cell state (meaningful on gate-0 lanes) ---------------------
  float c_old[4];
  #pragma unroll
  for (int r = 0; r < 4; ++r) {
    int b_r = 16 * mt + (l >> 4) * 4 + r;
    c_old[r] = c0[(size_t)b_r * UNITS + u0 + ct * 4 + (l & 3)];
  }

  // ---- stage h0 (fp32 -> bf16), padded rows ---------------------------------
  {
    int r = tid >> 4, cq = tid & 15;
    const float* src = h0 + (size_t)r * UNITS;
    #pragma unroll
    for (int i = 0; i < 4; ++i) {
      int c = i * 16 + cq;          // 16B group index 0..63
      float4 v0 = *(const float4*)(src + c * 8);
      float4 v1 = *(const float4*)(src + c * 8 + 4);
      short8 pk;
      pk[0]=(short)f2bf(v0.x); pk[1]=(short)f2bf(v0.y);
      pk[2]=(short)f2bf(v0.z); pk[3]=(short)f2bf(v0.w);
      pk[4]=(short)f2bf(v1.x); pk[5]=(short)f2bf(v1.y);
      pk[6]=(short)f2bf(v1.z); pk[7]=(short)f2bf(v1.w);
      *(short8*)(&hs[r * HSTR + c * 8]) = pk;
    }
  }
  __syncthreads();

  // per-lane constants
  const int arow  = 16 * mt + (l & 15);
  const unsigned short* hsrow = hs + arow * HSTR;
  const int agrp0 = l >> 4;
  const int sr = tid >> 4, scq = tid & 15;          // poll/commit mapping
  unsigned short* const hs_dst = hs + sr * HSTR + scq * 8;
  const bool isg = ((l & 15) >> 2) == 2;            // gate 2 = tanh
  const float An = isg ? 2.f : 1.f;
  const float Cn = isg ? -1.f : 0.f;
  const float Bn = isg ? -2.f : -1.f;
  const size_t ZXT = (size_t)NW1 * BATCH * 16;
  const size_t zbase = ((size_t)(4 * w + ct) * BATCH + 16 * mt + (l >> 4) * 4) * 16
                       + ((l & 15) >> 2) * 4 + (l & 3);

  for (int t = 0; t < SEQ; ++t) {
    // prefetch zx for this step (plain cached; zx2 static per launch)
    unsigned short zxr[4];
    #pragma unroll
    for (int r = 0; r < 4; ++r) zxr[r] = zxd[(size_t)t * ZXT + zbase + r * 16];

    if (t > 0) {
      // ---- data-flow poll: burst (sc0 -> local L2), straggler retries ------
      const unsigned short* src =
          hring + ((size_t)(t - 1) * BATCH + sr) * UNITS + scq * 8;
      u32x4 g0, g1, g2, g3;
      asm volatile("global_load_dwordx4 %0, %1, off sc0"            : "=&v"(g0) : "v"(src) : "memory");
      asm volatile("global_load_dwordx4 %0, %1, off offset:256 sc0" : "=&v"(g1) : "v"(src) : "memory");
      asm volatile("global_load_dwordx4 %0, %1, off offset:512 sc0" : "=&v"(g2) : "v"(src) : "memory");
      asm volatile("global_load_dwordx4 %0, %1, off offset:768 sc0" : "=&v"(g3) : "v"(src) : "memory");
      asm volatile("s_waitcnt vmcnt(0)" : "+v"(g0), "+v"(g1), "+v"(g2), "+v"(g3));
      __builtin_amdgcn_sched_barrier(0);
      unsigned b0 = chk4(g0), b1 = chk4(g1), b2 = chk4(g2), b3 = chk4(g3);
      int guard = 0;
      while ((b0 | b1 | b2 | b3) && ++guard < (1 << 20)) {
        __builtin_amdgcn_s_sleep(1);
        if (guard & 1) {  // alternate coherence level: L2 / MALL
          if (b0) asm volatile("global_load_dwordx4 %0, %1, off sc0 sc1"            : "=&v"(g0) : "v"(src) : "memory");
          if (b1) asm volatile("global_load_dwordx4 %0, %1, off offset:256 sc0 sc1" : "=&v"(g1) : "v"(src) : "memory");
          if (b2) asm volatile("global_load_dwordx4 %0, %1, off offset:512 sc0 sc1" : "=&v"(g2) : "v"(src) : "memory");
          if (b3) asm volatile("global_load_dwordx4 %0, %1, off offset:768 sc0 sc1" : "=&v"(g3) : "v"(src) : "memory");
        } else {
          if (b0) asm volatile("global_load_dwordx4 %0, %1, off sc0"            : "=&v"(g0) : "v"(src) : "memory");
          if (b1) asm volatile("global_load_dwordx4 %0, %1, off offset:256 sc0" : "=&v"(g1) : "v"(src) : "memory");
          if (b2) asm volatile("global_load_dwordx4 %0, %1, off offset:512 sc0" : "=&v"(g2) : "v"(src) : "memory");
          if (b3) asm volatile("global_load_dwordx4 %0, %1, off offset:768 sc0" : "=&v"(g3) : "v"(src) : "memory");
        }
        asm volatile("s_waitcnt vmcnt(0)" : "+v"(g0), "+v"(g1), "+v"(g2), "+v"(g3));
        __builtin_amdgcn_sched_barrier(0);
        b0 = chk4(g0); b1 = chk4(g1); b2 = chk4(g2); b3 = chk4(g3);
      }
      // commit to LDS
      *(u32x4*)(hs_dst      ) = g0;
      *(u32x4*)(hs_dst + 128) = g1;
      *(u32x4*)(hs_dst + 256) = g2;
      *(u32x4*)(hs_dst + 384) = g3;
      __syncthreads();
    }

    // ---- z = h · (Uhi + Ulo) via MFMA, split accumulators ----
    f32x4 accA = {0.f, 0.f, 0.f, 0.f};
    f32x4 accB = {0.f, 0.f, 0.f, 0.f};
    #pragma unroll
    for (int s = 0; s < 16; ++s) {
      short8 a = *(const short8*)(hsrow + (4 * s + agrp0) * 8);
      accA = __builtin_amdgcn_mfma_f32_16x16x32_bf16(a, uhi[s], accA, 0, 0, 0);
      accB = __builtin_amdgcn_mfma_f32_16x16x32_bf16(a, ulo[s], accB, 0, 0, 0);
    }

    // ---- in-register gates: lanes l, l^4, l^8 hold the 4 gates of (b,u) ----
    float vv[4];
    #pragma unroll
    for (int r = 0; r < 4; ++r) {
      float z = accA[r] + accB[r] + bf2f(zxr[r]);
      float e = __expf(Bn * z);
      vv[r] = An * __builtin_amdgcn_rcpf(1.f + e) + Cn;   // sigma or tanh
    }
    float hn[4], cn[4];
    unsigned pk0[4], pk1[4];
    #pragma unroll
    for (int r = 0; r < 4; ++r) {
      float wv = __shfl_xor(vv[r], 8);
      float x1 = __shfl_xor(vv[r], 4);
      float x2 = __shfl_xor(wv,    4);
      cn[r] = x1 * c_old[r] + vv[r] * wv;
      c_old[r] = cn[r];
      float e2 = __expf(-2.f * cn[r]);
      float th = 2.f * __builtin_amdgcn_rcpf(1.f + e2) - 1.f;
      hn[r] = x2 * th;
      unsigned hb = (unsigned)f2bf(hn[r]);
      unsigned d  = (hb & 0xFFFFu) | (__shfl_xor((int)hb, 1) << 16);
      unsigned d2 = (unsigned)__shfl_xor((int)d, 2);
      pk0[r] = d; pk1[r] = d2;
    }

    // publish h: 8B write-through stores (lane l&15==0), scope by placement
    if ((l & 15) == 0) {
      #pragma unroll
      for (int r = 0; r < 4; ++r) {
        int b_r = 16 * mt + (l >> 4) * 4 + r;
        unsigned short* dst = hring + ((size_t)t * BATCH + b_r) * UNITS + u0 + ct * 4;
        u32x2 pk; pk[0] = pk0[r]; pk[1] = pk1[r];
        if (loc)
          asm volatile("global_store_dwordx2 %0, %1, off sc0"
                       :: "v"(dst), "v"(pk) : "memory");
        else
          asm volatile("global_store_dwordx2 %0, %1, off sc0 sc1"
                       :: "v"(dst), "v"(pk) : "memory");
      }
    }

    // out writes (off the sync path), gate-0 lanes
    if ((l & 15) < 4) {
      int sidx = dir ? (SEQ - 1 - t) : t;
      #pragma unroll
      for (int r = 0; r < 4; ++r) {
        int b_r = 16 * mt + (l >> 4) * 4 + r;
        size_t oi = ((size_t)b_r * SEQ + sidx) * 1024 + dir * 512 + u0 + ct * 4 + (l & 3);
        __builtin_nontemporal_store(hn[r], &out[oi]);
      }
      if (t == SEQ - 1) {
        size_t base = (size_t)BATCH * SEQ * 1024;
        #pragma unroll
        for (int r = 0; r < 4; ++r) {
          int b_r = 16 * mt + (l >> 4) * 4 + r;
          size_t o1 = base + (size_t)(2*dir  ) * BATCH * UNITS + (size_t)b_r * UNITS + u0 + ct * 4 + (l & 3);
          size_t o2 = base + (size_t)(2*dir+1) * BATCH * UNITS + (size_t)b_r * UNITS + u0 + ct * 4 + (l & 3);
          __builtin_nontemporal_store(hn[r], &out[o1]);
          __builtin_nontemporal_store(cn[r], &out[o2]);
        }
      }
    }
  }
}

// -------------------- launch ----------------------------------------------
extern "C" void kernel_launch(void* const* d_in, const int* in_sizes, int n_in,
                              void* d_out, int out_size, void* d_ws, size_t ws_size,
                              hipStream_t stream)
{
  const int*   x   = (const int*)  d_in[0];
  const float* fh  = (const float*)d_in[1];
  const float* fc  = (const float*)d_in[2];
  const float* bh  = (const float*)d_in[3];
  const float* bc  = (const float*)d_in[4];
  const float* emb = (const float*)d_in[5];
  const float* Wf  = (const float*)d_in[6];
  const float* Uf  = (const float*)d_in[7];
  const float* bf  = (const float*)d_in[8];
  const float* Wb  = (const float*)d_in[9];
  const float* Ub  = (const float*)d_in[10];
  const float* bb  = (const float*)d_in[11];
  float* out = (float*)d_out;

  if (ws_size < FLG_OFF + FLG_BYTES) return;

  unsigned short* zx2   = (unsigned short*)((char*)d_ws + ZX2_OFF);
  unsigned short* hring = (unsigned short*)((char*)d_ws + HB_OFF);
  int*            claim = (int*)((char*)d_ws + FLG_OFF);

  // sentinel-fill h ring (0xFFFF = not ready) + zero claim flags
  hipMemsetAsync(hring, 0xFF, HB_BYTES, stream);
  hipMemsetAsync(claim, 0, FLG_BYTES, stream);
  k_zx  <<<dim3(32, 256, 2), 256, 0, stream>>>(x, emb, Wf, bf, Wb, bb, zx2);
  k_rec2<<<dim3(256), NTHR, 0, stream>>>(fh, fc, bh, bc, Uf, Ub, zx2, hring, claim, out);
}